// Round 10
// baseline (278.799 us; speedup 1.0000x reference)
//
#include <hip/hip_runtime.h>
#include <hip/hip_bf16.h>
#include <hip/hip_fp8.h>

#define N_NODES 50000
#define M_PAD   50048          // 782 * 64
#define N_EDGES 800000
#define NEG_SLOPE 0.2f

#define EPT 8                                            // edges per thread (bucketA)
#define BKA 391                                          // ceil(800000 / (256*8)) bucketA blocks
#define NBUCK 256                                        // dst buckets
#define NPB 196                                          // nodes per bucket (256*196 = 50176 >= 50000)
#define SEGCAP 40                                        // per-(block,bucket) segment capacity
#define GBLK 782                                         // GEMM1 blocks (64 rows x 256 cols, 512 thr)

typedef __attribute__((ext_vector_type(8))) short bf16x8;
typedef __attribute__((ext_vector_type(4))) float f32x4;
typedef __attribute__((ext_vector_type(2))) float f32x2;

__device__ __forceinline__ unsigned short f2bf(float f) {
    unsigned u = __float_as_uint(f);
    u += 0x7FFFu + ((u >> 16) & 1u);          // RNE
    return (unsigned short)(u >> 16);
}
__device__ __forceinline__ float bf2f(unsigned short h) {
    return __uint_as_float(((unsigned)h) << 16);
}

// ---- fp8 e4m3 HW converts (gfx950 OCP) ----
#if __has_builtin(__builtin_amdgcn_cvt_pk_f32_fp8)
__device__ __forceinline__ f32x2 fp8pk_lo(unsigned int p) { return __builtin_amdgcn_cvt_pk_f32_fp8(p, false); }
__device__ __forceinline__ f32x2 fp8pk_hi(unsigned int p) { return __builtin_amdgcn_cvt_pk_f32_fp8(p, true); }
#else
__device__ __forceinline__ float fp82f_s(unsigned char b) {
    __hip_fp8_e4m3 t; t.__x = (__hip_fp8_storage_t)b; return (float)t;
}
__device__ __forceinline__ f32x2 fp8pk_lo(unsigned int p) {
    f32x2 r; r.x = fp82f_s(p & 0xff); r.y = fp82f_s((p >> 8) & 0xff); return r;
}
__device__ __forceinline__ f32x2 fp8pk_hi(unsigned int p) {
    f32x2 r; r.x = fp82f_s((p >> 16) & 0xff); r.y = fp82f_s(p >> 24); return r;
}
#endif

#if __has_builtin(__builtin_amdgcn_cvt_pk_fp8_f32)
__device__ __forceinline__ unsigned int fp8enc2(float a, float b) {
    return (unsigned int)__builtin_amdgcn_cvt_pk_fp8_f32(a, b, 0, false);
}
#else
__device__ __forceinline__ unsigned int fp8enc2(float a, float b) {
    __hip_fp8_e4m3 ta(a), tb(b);
    return (unsigned int)ta.__x | ((unsigned int)tb.__x << 8);
}
#endif

// ---------------- trans: W transpose + xb cast + bucket_total zero (grid dim3(10,80)) ----------------

__global__ __launch_bounds__(256) void k_trans(const float* __restrict__ W1, const float* __restrict__ W2,
                                               const float* __restrict__ resW2, const float* __restrict__ x,
                                               unsigned short* __restrict__ W1T, unsigned short* __restrict__ W2T,
                                               unsigned short* __restrict__ xb, unsigned int* __restrict__ btot) {
    int flat = blockIdx.y * 10 + blockIdx.x;    // 0..799
    if (flat == 0) btot[threadIdx.x] = 0;

    if (blockIdx.y < 8) {
        __shared__ unsigned short tile[32][33];
        int bx = blockIdx.x;
        const float* in;
        unsigned short* out;
        int Nn, n0;
        if (bx < 8)      { in = W1;    out = W1T;            Nn = 256; n0 = bx * 32; }
        else if (bx == 8){ in = W2;    out = W2T;            Nn = 32;  n0 = 0; }
        else             { in = resW2; out = W2T + 32 * 256; Nn = 32;  n0 = 0; }
        int k0 = blockIdx.y * 32;
        int tx = threadIdx.x & 31, ty = threadIdx.x >> 5;
        #pragma unroll
        for (int r = 0; r < 4; ++r) {
            int k = k0 + ty + r * 8;
            tile[ty + r * 8][tx] = f2bf(in[(size_t)k * Nn + n0 + tx]);
        }
        __syncthreads();
        #pragma unroll
        for (int r = 0; r < 4; ++r) {
            int n = ty + r * 8;
            out[(size_t)(n0 + n) * 256 + k0 + tx] = tile[tx][n];
        }
    } else {
        int xid = flat - 80;                    // 0..719
        const size_t NCHUNK = (size_t)M_PAD * 256 / 8;
        for (size_t c = (size_t)xid * 256 + threadIdx.x; c < NCHUNK; c += (size_t)720 * 256) {
            size_t base = c * 8;
            float4 a = make_float4(0.f, 0.f, 0.f, 0.f), b = a;
            if (base < (size_t)N_NODES * 256) {
                a = *(const float4*)(x + base);
                b = *(const float4*)(x + base + 4);
            }
            ushort4 h0, h1;
            h0.x = f2bf(a.x); h0.y = f2bf(a.y); h0.z = f2bf(a.z); h0.w = f2bf(a.w);
            h1.x = f2bf(b.x); h1.y = f2bf(b.y); h1.z = f2bf(b.z); h1.w = f2bf(b.w);
            *(ushort4*)(xb + base) = h0;
            *(ushort4*)(xb + base + 4) = h1;
        }
    }
}

// ---------------- GEMM1 body (64 rows x 256 cols with 8 waves; bn0=0) — round-3 verified math ----------------

__device__ __forceinline__ void gemm1_half(int g, int bn0,
                                           const unsigned short* __restrict__ xb,
                                           const unsigned short* __restrict__ BT,
                                           const float* __restrict__ al1, const float* __restrict__ ar1,
                                           unsigned char* __restrict__ Cb8,
                                           float* __restrict__ el1, float* __restrict__ er1) {
    const int t = threadIdx.x;
    const int bm0 = g * 64;
    const int wave = t >> 6, lane = t & 63;
    const int wm = (wave & 1) * 32, wn = (wave >> 1) * 64;
    const int lm = lane & 15, quad = lane >> 4;

    f32x4 acc[2][4];
    #pragma unroll
    for (int i = 0; i < 2; ++i)
        #pragma unroll
        for (int j = 0; j < 4; ++j)
            #pragma unroll
            for (int r = 0; r < 4; ++r) acc[i][j][r] = 0.f;

    const unsigned short* bp[4];
    const unsigned short* ap[2];
    #pragma unroll
    for (int i = 0; i < 4; ++i)
        bp[i] = BT + (size_t)(bn0 + wn + i * 16 + lm) * 256 + quad * 8;
    #pragma unroll
    for (int i = 0; i < 2; ++i)
        ap[i] = xb + (size_t)(bm0 + wm + i * 16 + lm) * 256 + quad * 8;

    bf16x8 nb[4], na[2];
    #pragma unroll
    for (int i = 0; i < 4; ++i) nb[i] = *(const bf16x8*)(bp[i]);
    #pragma unroll
    for (int i = 0; i < 2; ++i) na[i] = *(const bf16x8*)(ap[i]);

    #pragma unroll
    for (int k0 = 0; k0 < 256; k0 += 32) {
        bf16x8 cb[4], ca[2];
        #pragma unroll
        for (int i = 0; i < 4; ++i) cb[i] = nb[i];
        #pragma unroll
        for (int i = 0; i < 2; ++i) ca[i] = na[i];
        if (k0 + 32 < 256) {
            #pragma unroll
            for (int i = 0; i < 4; ++i) nb[i] = *(const bf16x8*)(bp[i] + k0 + 32);
            #pragma unroll
            for (int i = 0; i < 2; ++i) na[i] = *(const bf16x8*)(ap[i] + k0 + 32);
        }
        #pragma unroll
        for (int mi = 0; mi < 2; ++mi)
            #pragma unroll
            for (int ni = 0; ni < 4; ++ni)
                acc[mi][ni] = __builtin_amdgcn_mfma_f32_16x16x32_bf16(ca[mi], cb[ni], acc[mi][ni], 0, 0, 0);
    }

    #pragma unroll
    for (int mi = 0; mi < 2; ++mi) {
        #pragma unroll
        for (int ni = 0; ni < 4; ++ni) {
            int col = bn0 + wn + ni * 16 + lm;
            int row0 = bm0 + wm + mi * 16 + quad * 4;
            unsigned int p01 = fp8enc2(acc[mi][ni][0], acc[mi][ni][1]);
            unsigned int p23 = fp8enc2(acc[mi][ni][2], acc[mi][ni][3]);
            Cb8[(size_t)(row0 + 0) * 256 + col] = (unsigned char)(p01 & 0xff);
            Cb8[(size_t)(row0 + 1) * 256 + col] = (unsigned char)((p01 >> 8) & 0xff);
            Cb8[(size_t)(row0 + 2) * 256 + col] = (unsigned char)(p23 & 0xff);
            Cb8[(size_t)(row0 + 3) * 256 + col] = (unsigned char)((p23 >> 8) & 0xff);
        }
    }
    float alv[4], arv[4];
    #pragma unroll
    for (int ni = 0; ni < 4; ++ni) {
        int colg = bn0 + wn + ni * 16 + lm;
        alv[ni] = al1[colg];
        arv[ni] = ar1[colg];
    }
    int head0 = (bn0 + wn) >> 5;
    #pragma unroll
    for (int gg = 0; gg < 2; ++gg) {
        #pragma unroll
        for (int mi = 0; mi < 2; ++mi) {
            #pragma unroll
            for (int r = 0; r < 4; ++r) {
                float pel = acc[mi][2 * gg][r] * alv[2 * gg] + acc[mi][2 * gg + 1][r] * alv[2 * gg + 1];
                float per = acc[mi][2 * gg][r] * arv[2 * gg] + acc[mi][2 * gg + 1][r] * arv[2 * gg + 1];
                #pragma unroll
                for (int m = 1; m <= 8; m <<= 1) {
                    pel += __shfl_xor(pel, m, 64);
                    per += __shfl_xor(per, m, 64);
                }
                if (lm == 0) {
                    int row = bm0 + wm + mi * 16 + quad * 4 + r;
                    el1[row * 8 + head0 + gg] = pel;
                    er1[row * 8 + head0 + gg] = per;
                }
            }
        }
    }
}

// ---------------- GEMM1: standalone, 512 threads = 8 waves cover all 256 cols ----------------

__global__ __launch_bounds__(512) void k_gemm1(const unsigned short* __restrict__ xb,
                                               const unsigned short* __restrict__ BT,
                                               const float* __restrict__ al1, const float* __restrict__ ar1,
                                               unsigned char* __restrict__ Cb8,
                                               float* __restrict__ el1, float* __restrict__ er1) {
    gemm1_half(blockIdx.x, 0, xb, BT, al1, ar1, Cb8, el1, er1);
}

// ---------------- bucketA: LDS counting sort phase A (standalone) ----------------

__global__ __launch_bounds__(256) void k_bucketA(const int* __restrict__ src, const int* __restrict__ dst,
                                                 uint2* __restrict__ seg, unsigned int* __restrict__ cnt,
                                                 unsigned int* __restrict__ btot) {
    __shared__ unsigned int lcnt[NBUCK];
    int vb = blockIdx.x;
    lcnt[threadIdx.x] = 0;
    __syncthreads();
    int base = vb * (256 * EPT) + threadIdx.x;
    int sv[EPT], dv[EPT], bk[EPT], lr[EPT];
    #pragma unroll
    for (int q = 0; q < EPT; ++q) {
        int i = base + q * 256;
        if (i < N_EDGES) { sv[q] = src[i]; dv[q] = dst[i]; }
        else dv[q] = -1;
    }
    #pragma unroll
    for (int q = 0; q < EPT; ++q) {
        if (dv[q] >= 0) {
            bk[q] = (int)((unsigned)dv[q] / NPB);
            lr[q] = atomicAdd(&lcnt[bk[q]], 1u);
        }
    }
    __syncthreads();
    cnt[vb * NBUCK + threadIdx.x] = lcnt[threadIdx.x];
    if (lcnt[threadIdx.x] > 0) atomicAdd(&btot[threadIdx.x], lcnt[threadIdx.x]);
    #pragma unroll
    for (int q = 0; q < EPT; ++q) {
        if (dv[q] >= 0 && lr[q] < SEGCAP) {
            size_t slot = ((size_t)bk[q] * BKA + vb) * SEGCAP + lr[q];
            seg[slot] = make_uint2((unsigned)sv[q], (unsigned)dv[q] - (unsigned)bk[q] * NPB);
        }
    }
}

// ---------------- bucketB: rowoff + csr build (standalone, one block per bucket) ----------------

__global__ __launch_bounds__(256) void k_bucketB(const uint2* __restrict__ seg, const unsigned int* __restrict__ cnt,
                                                 const unsigned int* __restrict__ btot,
                                                 int* __restrict__ rowoff, int* __restrict__ csr_src) {
    __shared__ unsigned int hist[NPB];
    __shared__ unsigned int cursor[NPB];
    __shared__ unsigned int red[256];
    int b = blockIdx.x;
    int t = threadIdx.x;
    if (t < NPB) hist[t] = 0;
    red[t] = (t < b) ? btot[t] : 0;
    __syncthreads();
    #pragma unroll
    for (int off = 128; off > 0; off >>= 1) {
        if (t < off) red[t] += red[t + off];
        __syncthreads();
    }
    unsigned int base = red[0];
    __syncthreads();
    // pass 1: count
    for (int s = t; s < BKA; s += 256) {
        unsigned int c = cnt[s * NBUCK + b];
        const uint2* sp = seg + ((size_t)b * BKA + s) * SEGCAP;
        for (unsigned int j = 0; j < c; ++j) {
            atomicAdd(&hist[sp[j].y], 1u);
        }
    }
    __syncthreads();
    // exclusive scan of hist[NPB] via Hillis-Steele in red[]
    red[t] = (t < NPB) ? hist[t] : 0;
    __syncthreads();
    for (int off = 1; off < 256; off <<= 1) {
        unsigned int val = (t >= off) ? red[t - off] : 0;
        __syncthreads();
        red[t] += val;
        __syncthreads();
    }
    if (t < NPB) {
        unsigned int excl = red[t] - hist[t];
        cursor[t] = excl;
        int v = b * NPB + t;
        if (v < N_NODES) rowoff[v] = (int)(base + excl);
    }
    if (b == NBUCK - 1 && t == 0) rowoff[N_NODES] = N_EDGES;
    __syncthreads();
    // pass 2: place
    for (int s = t; s < BKA; s += 256) {
        unsigned int c = cnt[s * NBUCK + b];
        const uint2* sp = seg + ((size_t)b * BKA + s) * SEGCAP;
        for (unsigned int j = 0; j < c; ++j) {
            uint2 eg = sp[j];
            unsigned int r = atomicAdd(&cursor[eg.y], 1u);
            csr_src[base + r] = (int)eg.x;
        }
    }
}

// ---------------- L1 aggregation: one wave per dst node, shuffle-shared softmax weights ----------------

__global__ __launch_bounds__(256) void k_agg1(const unsigned char* __restrict__ feat8,
                                              const float* __restrict__ el1, const float* __restrict__ er1,
                                              const unsigned short* __restrict__ xb, const float* __restrict__ b1,
                                              const int* __restrict__ rowoff, const int* __restrict__ csr_src,
                                              unsigned short* __restrict__ y_b) {
    int v = (blockIdx.x * 256 + threadIdx.x) >> 6;
    int lane = threadIdx.x & 63;
    if (v >= M_PAD) return;
    int c0 = lane * 4;
    if (v >= N_NODES) {
        ushort4 z = {0, 0, 0, 0};
        *(ushort4*)(y_b + (size_t)v * 256 + c0) = z;
        return;
    }
    int h = lane >> 3;
    float er  = er1[v * 8 + h];
    float erc = er1[v * 8 + (lane & 7)];
    float ax = 0.f, ay = 0.f, az = 0.f, aw = 0.f, wsum = 0.f;
    int s = rowoff[v], e = rowoff[v + 1];
    int j = s;
    for (; j + 7 < e; j += 8) {
        int um = csr_src[j + (lane >> 3)];
        float elv = el1[um * 8 + (lane & 7)];
        int u[8];
        #pragma unroll
        for (int q = 0; q < 8; ++q) u[q] = __shfl(um, q * 8);
        unsigned int hv[8];
        #pragma unroll
        for (int q = 0; q < 8; ++q) hv[q] = *(const unsigned int*)(feat8 + (size_t)u[q] * 256 + c0);
        float tq = elv + erc;
        tq = fmaxf(tq, NEG_SLOPE * tq);
        float wv = __expf(tq);
        #pragma unroll
        for (int q = 0; q < 8; ++q) {
            float w = __shfl(wv, q * 8 + h);
            wsum += w;
            f32x2 lo = fp8pk_lo(hv[q]);
            f32x2 hi = fp8pk_hi(hv[q]);
            ax += w * lo.x; ay += w * lo.y; az += w * hi.x; aw += w * hi.y;
        }
    }
    for (; j + 3 < e; j += 4) {
        int u[4];
        #pragma unroll
        for (int q = 0; q < 4; ++q) u[q] = csr_src[j + q];
        float tt[4];
        #pragma unroll
        for (int q = 0; q < 4; ++q) tt[q] = el1[u[q] * 8 + h] + er;
        unsigned int hv[4];
        #pragma unroll
        for (int q = 0; q < 4; ++q) hv[q] = *(const unsigned int*)(feat8 + (size_t)u[q] * 256 + c0);
        #pragma unroll
        for (int q = 0; q < 4; ++q) {
            float tq = fmaxf(tt[q], NEG_SLOPE * tt[q]);
            float w = __expf(tq);
            wsum += w;
            f32x2 lo = fp8pk_lo(hv[q]);
            f32x2 hi = fp8pk_hi(hv[q]);
            ax += w * lo.x; ay += w * lo.y; az += w * hi.x; aw += w * hi.y;
        }
    }
    for (; j < e; ++j) {
        int u = csr_src[j];
        float tt = el1[u * 8 + h] + er;
        unsigned int hh = *(const unsigned int*)(feat8 + (size_t)u * 256 + c0);
        tt = fmaxf(tt, NEG_SLOPE * tt);
        float w = __expf(tt);
        wsum += w;
        f32x2 lo = fp8pk_lo(hh);
        f32x2 hi = fp8pk_hi(hh);
        ax += w * lo.x; ay += w * lo.y; az += w * hi.x; aw += w * hi.y;
    }
    float inv = (e > s) ? 1.f / wsum : 0.f;
    ushort4 rh = *(const ushort4*)(xb + (size_t)v * 256 + c0);
    float4 bb = *(const float4*)(b1 + c0);
    ushort4 o;
    o.x = f2bf(fmaxf(ax * inv + bf2f(rh.x) + bb.x, 0.f));
    o.y = f2bf(fmaxf(ay * inv + bf2f(rh.y) + bb.y, 0.f));
    o.z = f2bf(fmaxf(az * inv + bf2f(rh.z) + bb.z, 0.f));
    o.w = f2bf(fmaxf(aw * inv + bf2f(rh.w) + bb.w, 0.f));
    *(ushort4*)(y_b + (size_t)v * 256 + c0) = o;
}

// ---------------- GEMM2 + fused elr2: 64x64 blocks, prefetch pipeline ----------------

__global__ __launch_bounds__(256) void k_gemm2f(const unsigned short* __restrict__ Ab,
                                                const unsigned short* __restrict__ BT,  // [64][256]
                                                const float* __restrict__ al2, const float* __restrict__ ar2,
                                                unsigned short* __restrict__ feat2b, float* __restrict__ res2,
                                                float* __restrict__ el2, float* __restrict__ er2) {
    const int t = threadIdx.x;
    const int bm0 = blockIdx.x * 64;
    const int wave = t >> 6, lane = t & 63;
    const int wm = (wave & 1) * 32, wn = (wave >> 1) * 32;
    const int lm = lane & 15, quad = lane >> 4;

    f32x4 acc[2][2];
    #pragma unroll
    for (int i = 0; i < 2; ++i)
        #pragma unroll
        for (int j = 0; j < 2; ++j)
            #pragma unroll
            for (int r = 0; r < 4; ++r) acc[i][j][r] = 0.f;

    const unsigned short* bp[2];
    const unsigned short* ap[2];
    #pragma unroll
    for (int i = 0; i < 2; ++i) {
        bp[i] = BT + (size_t)(wn + i * 16 + lm) * 256 + quad * 8;
        ap[i] = Ab + (size_t)(bm0 + wm + i * 16 + lm) * 256 + quad * 8;
    }

    bf16x8 nb[2], na[2];
    #pragma unroll
    for (int i = 0; i < 2; ++i) { nb[i] = *(const bf16x8*)(bp[i]); na[i] = *(const bf16x8*)(ap[i]); }

    #pragma unroll
    for (int k0 = 0; k0 < 256; k0 += 32) {
        bf16x8 cb[2], ca[2];
        #pragma unroll
        for (int i = 0; i < 2; ++i) { cb[i] = nb[i]; ca[i] = na[i]; }
        if (k0 + 32 < 256) {
            #pragma unroll
            for (int i = 0; i < 2; ++i) {
                nb[i] = *(const bf16x8*)(bp[i] + k0 + 32);
                na[i] = *(const bf16x8*)(ap[i] + k0 + 32);
            }
        }
        #pragma unroll
        for (int mi = 0; mi < 2; ++mi)
            #pragma unroll
            for (int ni = 0; ni < 2; ++ni)
                acc[mi][ni] = __builtin_amdgcn_mfma_f32_16x16x32_bf16(ca[mi], cb[ni], acc[mi][ni], 0, 0, 0);
    }

    #pragma unroll
    for (int mi = 0; mi < 2; ++mi) {
        #pragma unroll
        for (int ni = 0; ni < 2; ++ni) {
            int col = wn + ni * 16 + lm;  // 0..63
            #pragma unroll
            for (int r = 0; r < 4; ++r) {
                int row = bm0 + wm + mi * 16 + quad * 4 + r;
                float val = acc[mi][ni][r];
                if (col < 32) feat2b[(size_t)row * 32 + col] = f2bf(val);
                else          res2[(size_t)row * 32 + col - 32] = val;
            }
        }
    }
    if (wn == 0) {
        float alv[2], arv[2];
        #pragma unroll
        for (int ni = 0; ni < 2; ++ni) {
            alv[ni] = al2[ni * 16 + lm];
            arv[ni] = ar2[ni * 16 + lm];
        }
        #pragma unroll
        for (int mi = 0; mi < 2; ++mi) {
            #pragma unroll
            for (int r = 0; r < 4; ++r) {
                float pel = acc[mi][0][r] * alv[0] + acc[mi][1][r] * alv[1];
                float per = acc[mi][0][r] * arv[0] + acc[mi][1][r] * arv[1];
                #pragma unroll
                for (int m = 1; m <= 8; m <<= 1) {
                    pel += __shfl_xor(pel, m, 64);
                    per += __shfl_xor(per, m, 64);
                }
                if (lm == 0) {
                    int row = bm0 + wm + mi * 16 + quad * 4 + r;
                    el2[row] = pel;
                    er2[row] = per;
                }
            }
        }
    }
}

// ---------------- L2 aggregation ----------------

__global__ __launch_bounds__(256) void k_agg2(const unsigned short* __restrict__ feat2b,
                                              const float* __restrict__ el2, const float* __restrict__ er2,
                                              const float* __restrict__ res2, const float* __restrict__ b2,
                                              const int* __restrict__ rowoff, const int* __restrict__ csr_src,
                                              float* __restrict__ out) {
    int g = blockIdx.x * 256 + threadIdx.x;
    int v = g >> 5;
    int c = g & 31;
    if (v >= N_NODES) return;
    float er = er2[v];
    float acc = 0.f, wsum = 0.f;
    int s = rowoff[v], e = rowoff[v + 1];
    int j = s;
    for (; j + 3 < e; j += 4) {
        int u[4];
        #pragma unroll
        for (int q = 0; q < 4; ++q) u[q] = csr_src[j + q];
        float tt[4];
        #pragma unroll
        for (int q = 0; q < 4; ++q) tt[q] = el2[u[q]] + er;
        unsigned short fv[4];
        #pragma unroll
        for (int q = 0; q < 4; ++q) fv[q] = feat2b[(size_t)u[q] * 32 + c];
        #pragma unroll
        for (int q = 0; q < 4; ++q) {
            float tq = fmaxf(tt[q], NEG_SLOPE * tt[q]);
            float w = __expf(tq);
            wsum += w;
            acc += w * bf2f(fv[q]);
        }
    }
    for (; j < e; ++j) {
        int u = csr_src[j];
        float t = el2[u] + er;
        t = fmaxf(t, NEG_SLOPE * t);
        float w = __expf(t);
        wsum += w;
        acc += w * bf2f(feat2b[(size_t)u * 32 + c]);
    }
    float inv = (e > s) ? 1.f / wsum : 0.f;
    out[(size_t)v * 32 + c] = acc * inv + res2[(size_t)v * 32 + c] + b2[c];
}

// ---------------- launch ----------------

extern "C" void kernel_launch(void* const* d_in, const int* in_sizes, int n_in,
                              void* d_out, int out_size, void* d_ws, size_t ws_size,
                              hipStream_t stream) {
    const float* x     = (const float*)d_in[0];
    const int*   src   = (const int*)d_in[1];
    const int*   dst   = (const int*)d_in[2];
    const float* W1    = (const float*)d_in[3];
    const float* al1   = (const float*)d_in[4];
    const float* ar1   = (const float*)d_in[5];
    const float* b1    = (const float*)d_in[6];
    const float* W2    = (const float*)d_in[7];
    const float* al2   = (const float*)d_in[8];
    const float* ar2   = (const float*)d_in[9];
    const float* resW2 = (const float*)d_in[10];
    const float* b2    = (const float*)d_in[11];
    float* out = (float*)d_out;

    char* ws = (char*)d_ws;
    size_t off = 0;
    auto alloc = [&](size_t bytes) {
        void* p = ws + off;
        off += (bytes + 255) & ~(size_t)255;
        return p;
    };
    unsigned short* xb     = (unsigned short*)alloc((size_t)M_PAD * 256 * 2);
    unsigned char*  feat8  = (unsigned char*)alloc((size_t)M_PAD * 256);
    unsigned short* y_b    = (unsigned short*)alloc((size_t)M_PAD * 256 * 2);
    unsigned short* W1T    = (unsigned short*)alloc((size_t)256 * 256 * 2);
    unsigned short* W2T    = (unsigned short*)alloc((size_t)64 * 256 * 2);
    unsigned short* feat2b = (unsigned short*)alloc((size_t)M_PAD * 32 * 2);
    float* res2   = (float*)alloc((size_t)M_PAD * 32 * 4);
    float* el1    = (float*)alloc((size_t)M_PAD * 8 * 4);
    float* er1    = (float*)alloc((size_t)M_PAD * 8 * 4);
    float* el2    = (float*)alloc((size_t)M_PAD * 4);
    float* er2    = (float*)alloc((size_t)M_PAD * 4);
    int*   rowoff = (int*)alloc((size_t)(N_NODES + 1) * 4);
    int*   csr    = (int*)alloc((size_t)N_EDGES * 4);
    uint2* seg    = (uint2*)alloc((size_t)NBUCK * BKA * SEGCAP * 8);
    unsigned int* cnt  = (unsigned int*)alloc((size_t)BKA * NBUCK * 4);
    unsigned int* btot = (unsigned int*)alloc((size_t)NBUCK * 4);
    (void)ws_size;

    // trans: W transpose + xb cast + btot zero
    k_trans<<<dim3(10, 80), 256, 0, stream>>>(W1, W2, resW2, x, W1T, W2T, xb, btot);

    // CSR build phase A (standalone — measurable)
    k_bucketA<<<BKA, 256, 0, stream>>>(src, dst, seg, cnt, btot);

    // GEMM1 standalone: 782 blocks x 512 threads, full 256-col width (xb read once)
    k_gemm1<<<GBLK, 512, 0, stream>>>(xb, W1T, al1, ar1, feat8, el1, er1);

    // CSR build phase B (standalone)
    k_bucketB<<<NBUCK, 256, 0, stream>>>(seg, cnt, btot, rowoff, csr);

    // Layer 1 aggregation
    k_agg1<<<(M_PAD * 64) / 256, 256, 0, stream>>>(feat8, el1, er1, xb, b1, rowoff, csr, y_b);

    // Layer 2
    k_gemm2f<<<M_PAD / 64, 256, 0, stream>>>(y_b, W2T, al2, ar2, feat2b, res2, el2, er2);
    k_agg2<<<(N_NODES * 32) / 256, 256, 0, stream>>>(feat2b, el2, er2, res2, b2, rowoff, csr, out);
}

// Round 11
// 251.017 us; speedup vs baseline: 1.1107x; 1.1107x over previous
//
#include <hip/hip_runtime.h>
#include <hip/hip_bf16.h>
#include <hip/hip_fp8.h>

#define N_NODES 50000
#define M_PAD   50048          // 782 * 64
#define N_EDGES 800000
#define NEG_SLOPE 0.2f

#define EPT 8                                            // edges per thread (bucketA)
#define BKA 391                                          // ceil(800000 / (256*8)) bucketA blocks
#define NBUCK 256                                        // dst buckets
#define NPB 196                                          // nodes per bucket (256*196 = 50176 >= 50000)
#define SEGCAP 40                                        // per-(block,bucket) segment capacity
#define GBLK 782                                         // GEMM1 blocks (64 rows x 256 cols, 512 thr)
#define APAD 264                                         // sA row stride in shorts (512B + 16B pad)

typedef __attribute__((ext_vector_type(8))) short bf16x8;
typedef __attribute__((ext_vector_type(4))) float f32x4;
typedef __attribute__((ext_vector_type(2))) float f32x2;

__device__ __forceinline__ unsigned short f2bf(float f) {
    unsigned u = __float_as_uint(f);
    u += 0x7FFFu + ((u >> 16) & 1u);          // RNE
    return (unsigned short)(u >> 16);
}
__device__ __forceinline__ float bf2f(unsigned short h) {
    return __uint_as_float(((unsigned)h) << 16);
}

// ---- fp8 e4m3 HW converts (gfx950 OCP) ----
#if __has_builtin(__builtin_amdgcn_cvt_pk_f32_fp8)
__device__ __forceinline__ f32x2 fp8pk_lo(unsigned int p) { return __builtin_amdgcn_cvt_pk_f32_fp8(p, false); }
__device__ __forceinline__ f32x2 fp8pk_hi(unsigned int p) { return __builtin_amdgcn_cvt_pk_f32_fp8(p, true); }
#else
__device__ __forceinline__ float fp82f_s(unsigned char b) {
    __hip_fp8_e4m3 t; t.__x = (__hip_fp8_storage_t)b; return (float)t;
}
__device__ __forceinline__ f32x2 fp8pk_lo(unsigned int p) {
    f32x2 r; r.x = fp82f_s(p & 0xff); r.y = fp82f_s((p >> 8) & 0xff); return r;
}
__device__ __forceinline__ f32x2 fp8pk_hi(unsigned int p) {
    f32x2 r; r.x = fp82f_s((p >> 16) & 0xff); r.y = fp82f_s(p >> 24); return r;
}
#endif

#if __has_builtin(__builtin_amdgcn_cvt_pk_fp8_f32)
__device__ __forceinline__ unsigned int fp8enc2(float a, float b) {
    return (unsigned int)__builtin_amdgcn_cvt_pk_fp8_f32(a, b, 0, false);
}
#else
__device__ __forceinline__ unsigned int fp8enc2(float a, float b) {
    __hip_fp8_e4m3 ta(a), tb(b);
    return (unsigned int)ta.__x | ((unsigned int)tb.__x << 8);
}
#endif

// ---------------- trans: W transpose (W1 -> fragment-major W1F) + xb cast + btot zero ----------------

__global__ __launch_bounds__(256) void k_trans(const float* __restrict__ W1, const float* __restrict__ W2,
                                               const float* __restrict__ resW2, const float* __restrict__ x,
                                               unsigned short* __restrict__ W1F, unsigned short* __restrict__ W2T,
                                               unsigned short* __restrict__ xb, unsigned int* __restrict__ btot) {
    int flat = blockIdx.y * 10 + blockIdx.x;    // 0..799
    if (flat == 0) btot[threadIdx.x] = 0;

    if (blockIdx.y < 8) {
        __shared__ unsigned short tile[32][33];
        int bx = blockIdx.x;
        const float* in;
        int Nn, n0;
        if (bx < 8)      { in = W1;    Nn = 256; n0 = bx * 32; }
        else if (bx == 8){ in = W2;    Nn = 32;  n0 = 0; }
        else             { in = resW2; Nn = 32;  n0 = 0; }
        int k0 = blockIdx.y * 32;
        int tx = threadIdx.x & 31, ty = threadIdx.x >> 5;
        #pragma unroll
        for (int r = 0; r < 4; ++r) {
            int k = k0 + ty + r * 8;
            tile[ty + r * 8][tx] = f2bf(in[(size_t)k * Nn + n0 + tx]);
        }
        __syncthreads();
        #pragma unroll
        for (int r = 0; r < 4; ++r) {
            int n = ty + r * 8;
            unsigned short val = tile[tx][n];
            int col = n0 + n;
            int kk = k0 + tx;
            if (bx < 8) {
                // fragment-major: chunk ((col>>4)*8 + (kk>>5)) ; lane = ((kk>>3)&3)*16 + (col&15) ; j = kk&7
                size_t idx = (((size_t)(col >> 4) * 8 + (kk >> 5)) << 9)
                           + ((((kk >> 3) & 3) * 16 + (col & 15)) << 3) + (kk & 7);
                W1F[idx] = val;
            } else {
                unsigned short* out = (bx == 8) ? W2T : (W2T + 32 * 256);
                out[(size_t)col * 256 + kk] = val;
            }
        }
    } else {
        int xid = flat - 80;                    // 0..719
        const size_t NCHUNK = (size_t)M_PAD * 256 / 8;
        for (size_t c = (size_t)xid * 256 + threadIdx.x; c < NCHUNK; c += (size_t)720 * 256) {
            size_t base = c * 8;
            float4 a = make_float4(0.f, 0.f, 0.f, 0.f), b = a;
            if (base < (size_t)N_NODES * 256) {
                a = *(const float4*)(x + base);
                b = *(const float4*)(x + base + 4);
            }
            ushort4 h0, h1;
            h0.x = f2bf(a.x); h0.y = f2bf(a.y); h0.z = f2bf(a.z); h0.w = f2bf(a.w);
            h1.x = f2bf(b.x); h1.y = f2bf(b.y); h1.z = f2bf(b.z); h1.w = f2bf(b.w);
            *(ushort4*)(xb + base) = h0;
            *(ushort4*)(xb + base + 4) = h1;
        }
    }
}

// ---------------- GEMM1: coalesced operands — A via LDS stage, B via fragment-major W1F ----------------
// 782 blocks x 512 thr. Tile 64 rows x 256 cols, K=256. Per wave: 32 rows x 64 cols (acc[2][4]).

__global__ __launch_bounds__(512) void k_gemm1(const unsigned short* __restrict__ xb,
                                               const unsigned short* __restrict__ W1F,
                                               const float* __restrict__ al1, const float* __restrict__ ar1,
                                               unsigned char* __restrict__ Cb8,
                                               float* __restrict__ el1, float* __restrict__ er1) {
    __shared__ unsigned short sA[64 * APAD];   // 33 KB (rows padded +16B)
    const int t = threadIdx.x;
    const int bm0 = blockIdx.x * 64;
    const int wave = t >> 6, lane = t & 63;
    const int wm = (wave & 1) * 32, wn = (wave >> 1) * 64;
    const int lm = lane & 15, quad = lane >> 4;

    // stage A-tile: 64 rows x 32 chunks (16B), coalesced reads, padded LDS rows
    #pragma unroll
    for (int rr = 0; rr < 4; ++rr) {
        int ch = rr * 512 + t;                 // 0..2047
        int row = ch >> 5, w = ch & 31;
        bf16x8 vv = *(const bf16x8*)(xb + (size_t)(bm0 + row) * 256 + w * 8);
        *(bf16x8*)(sA + row * APAD + w * 8) = vv;
    }
    __syncthreads();

    f32x4 acc[2][4];
    #pragma unroll
    for (int i = 0; i < 2; ++i)
        #pragma unroll
        for (int j = 0; j < 4; ++j)
            #pragma unroll
            for (int r = 0; r < 4; ++r) acc[i][j][r] = 0.f;

    // B pointers: fragment-major, lane-contiguous (coalesced 1KB/instr)
    const unsigned short* bp[4];
    #pragma unroll
    for (int i = 0; i < 4; ++i)
        bp[i] = W1F + ((size_t)((wave >> 1) * 4 + i)) * 4096 + lane * 8;
    // A LDS fragment bases
    const unsigned short* ap[2];
    #pragma unroll
    for (int i = 0; i < 2; ++i)
        ap[i] = sA + (wm + i * 16 + lm) * APAD + quad * 8;

    bf16x8 nb[4];
    #pragma unroll
    for (int i = 0; i < 4; ++i) nb[i] = *(const bf16x8*)(bp[i]);

    #pragma unroll
    for (int q = 0; q < 8; ++q) {
        bf16x8 cb[4];
        #pragma unroll
        for (int i = 0; i < 4; ++i) cb[i] = nb[i];
        if (q < 7) {
            #pragma unroll
            for (int i = 0; i < 4; ++i) nb[i] = *(const bf16x8*)(bp[i] + (q + 1) * 512);
        }
        bf16x8 ca[2];
        #pragma unroll
        for (int i = 0; i < 2; ++i) ca[i] = *(const bf16x8*)(ap[i] + q * 32);
        #pragma unroll
        for (int mi = 0; mi < 2; ++mi)
            #pragma unroll
            for (int ni = 0; ni < 4; ++ni)
                acc[mi][ni] = __builtin_amdgcn_mfma_f32_16x16x32_bf16(ca[mi], cb[ni], acc[mi][ni], 0, 0, 0);
    }

    // epilogue: fp8 C-write + el/er (unchanged from verified version; bn0 = 0)
    #pragma unroll
    for (int mi = 0; mi < 2; ++mi) {
        #pragma unroll
        for (int ni = 0; ni < 4; ++ni) {
            int col = wn + ni * 16 + lm;
            int row0 = bm0 + wm + mi * 16 + quad * 4;
            unsigned int p01 = fp8enc2(acc[mi][ni][0], acc[mi][ni][1]);
            unsigned int p23 = fp8enc2(acc[mi][ni][2], acc[mi][ni][3]);
            Cb8[(size_t)(row0 + 0) * 256 + col] = (unsigned char)(p01 & 0xff);
            Cb8[(size_t)(row0 + 1) * 256 + col] = (unsigned char)((p01 >> 8) & 0xff);
            Cb8[(size_t)(row0 + 2) * 256 + col] = (unsigned char)(p23 & 0xff);
            Cb8[(size_t)(row0 + 3) * 256 + col] = (unsigned char)((p23 >> 8) & 0xff);
        }
    }
    float alv[4], arv[4];
    #pragma unroll
    for (int ni = 0; ni < 4; ++ni) {
        int colg = wn + ni * 16 + lm;
        alv[ni] = al1[colg];
        arv[ni] = ar1[colg];
    }
    int head0 = wn >> 5;
    #pragma unroll
    for (int gg = 0; gg < 2; ++gg) {
        #pragma unroll
        for (int mi = 0; mi < 2; ++mi) {
            #pragma unroll
            for (int r = 0; r < 4; ++r) {
                float pel = acc[mi][2 * gg][r] * alv[2 * gg] + acc[mi][2 * gg + 1][r] * alv[2 * gg + 1];
                float per = acc[mi][2 * gg][r] * arv[2 * gg] + acc[mi][2 * gg + 1][r] * arv[2 * gg + 1];
                #pragma unroll
                for (int m = 1; m <= 8; m <<= 1) {
                    pel += __shfl_xor(pel, m, 64);
                    per += __shfl_xor(per, m, 64);
                }
                if (lm == 0) {
                    int row = bm0 + wm + mi * 16 + quad * 4 + r;
                    el1[row * 8 + head0 + gg] = pel;
                    er1[row * 8 + head0 + gg] = per;
                }
            }
        }
    }
}

// ---------------- bucketA: LDS counting sort phase A (standalone) ----------------

__global__ __launch_bounds__(256) void k_bucketA(const int* __restrict__ src, const int* __restrict__ dst,
                                                 uint2* __restrict__ seg, unsigned int* __restrict__ cnt,
                                                 unsigned int* __restrict__ btot) {
    __shared__ unsigned int lcnt[NBUCK];
    int vb = blockIdx.x;
    lcnt[threadIdx.x] = 0;
    __syncthreads();
    int base = vb * (256 * EPT) + threadIdx.x;
    int sv[EPT], dv[EPT], bk[EPT], lr[EPT];
    #pragma unroll
    for (int q = 0; q < EPT; ++q) {
        int i = base + q * 256;
        if (i < N_EDGES) { sv[q] = src[i]; dv[q] = dst[i]; }
        else dv[q] = -1;
    }
    #pragma unroll
    for (int q = 0; q < EPT; ++q) {
        if (dv[q] >= 0) {
            bk[q] = (int)((unsigned)dv[q] / NPB);
            lr[q] = atomicAdd(&lcnt[bk[q]], 1u);
        }
    }
    __syncthreads();
    cnt[vb * NBUCK + threadIdx.x] = lcnt[threadIdx.x];
    if (lcnt[threadIdx.x] > 0) atomicAdd(&btot[threadIdx.x], lcnt[threadIdx.x]);
    #pragma unroll
    for (int q = 0; q < EPT; ++q) {
        if (dv[q] >= 0 && lr[q] < SEGCAP) {
            size_t slot = ((size_t)bk[q] * BKA + vb) * SEGCAP + lr[q];
            seg[slot] = make_uint2((unsigned)sv[q], (unsigned)dv[q] - (unsigned)bk[q] * NPB);
        }
    }
}

// ---------------- bucketB: rowoff + csr build (standalone, one block per bucket) ----------------

__global__ __launch_bounds__(256) void k_bucketB(const uint2* __restrict__ seg, const unsigned int* __restrict__ cnt,
                                                 const unsigned int* __restrict__ btot,
                                                 int* __restrict__ rowoff, int* __restrict__ csr_src) {
    __shared__ unsigned int hist[NPB];
    __shared__ unsigned int cursor[NPB];
    __shared__ unsigned int red[256];
    int b = blockIdx.x;
    int t = threadIdx.x;
    if (t < NPB) hist[t] = 0;
    red[t] = (t < b) ? btot[t] : 0;
    __syncthreads();
    #pragma unroll
    for (int off = 128; off > 0; off >>= 1) {
        if (t < off) red[t] += red[t + off];
        __syncthreads();
    }
    unsigned int base = red[0];
    __syncthreads();
    // pass 1: count
    for (int s = t; s < BKA; s += 256) {
        unsigned int c = cnt[s * NBUCK + b];
        const uint2* sp = seg + ((size_t)b * BKA + s) * SEGCAP;
        for (unsigned int j = 0; j < c; ++j) {
            atomicAdd(&hist[sp[j].y], 1u);
        }
    }
    __syncthreads();
    // exclusive scan of hist[NPB] via Hillis-Steele in red[]
    red[t] = (t < NPB) ? hist[t] : 0;
    __syncthreads();
    for (int off = 1; off < 256; off <<= 1) {
        unsigned int val = (t >= off) ? red[t - off] : 0;
        __syncthreads();
        red[t] += val;
        __syncthreads();
    }
    if (t < NPB) {
        unsigned int excl = red[t] - hist[t];
        cursor[t] = excl;
        int v = b * NPB + t;
        if (v < N_NODES) rowoff[v] = (int)(base + excl);
    }
    if (b == NBUCK - 1 && t == 0) rowoff[N_NODES] = N_EDGES;
    __syncthreads();
    // pass 2: place
    for (int s = t; s < BKA; s += 256) {
        unsigned int c = cnt[s * NBUCK + b];
        const uint2* sp = seg + ((size_t)b * BKA + s) * SEGCAP;
        for (unsigned int j = 0; j < c; ++j) {
            uint2 eg = sp[j];
            unsigned int r = atomicAdd(&cursor[eg.y], 1u);
            csr_src[base + r] = (int)eg.x;
        }
    }
}

// ---------------- L1 aggregation: one wave per dst node, shuffle-shared softmax weights ----------------

__global__ __launch_bounds__(256) void k_agg1(const unsigned char* __restrict__ feat8,
                                              const float* __restrict__ el1, const float* __restrict__ er1,
                                              const unsigned short* __restrict__ xb, const float* __restrict__ b1,
                                              const int* __restrict__ rowoff, const int* __restrict__ csr_src,
                                              unsigned short* __restrict__ y_b) {
    int v = (blockIdx.x * 256 + threadIdx.x) >> 6;
    int lane = threadIdx.x & 63;
    if (v >= M_PAD) return;
    int c0 = lane * 4;
    if (v >= N_NODES) {
        ushort4 z = {0, 0, 0, 0};
        *(ushort4*)(y_b + (size_t)v * 256 + c0) = z;
        return;
    }
    int h = lane >> 3;
    float er  = er1[v * 8 + h];
    float erc = er1[v * 8 + (lane & 7)];
    float ax = 0.f, ay = 0.f, az = 0.f, aw = 0.f, wsum = 0.f;
    int s = rowoff[v], e = rowoff[v + 1];
    int j = s;
    for (; j + 7 < e; j += 8) {
        int um = csr_src[j + (lane >> 3)];
        float elv = el1[um * 8 + (lane & 7)];
        int u[8];
        #pragma unroll
        for (int q = 0; q < 8; ++q) u[q] = __shfl(um, q * 8);
        unsigned int hv[8];
        #pragma unroll
        for (int q = 0; q < 8; ++q) hv[q] = *(const unsigned int*)(feat8 + (size_t)u[q] * 256 + c0);
        float tq = elv + erc;
        tq = fmaxf(tq, NEG_SLOPE * tq);
        float wv = __expf(tq);
        #pragma unroll
        for (int q = 0; q < 8; ++q) {
            float w = __shfl(wv, q * 8 + h);
            wsum += w;
            f32x2 lo = fp8pk_lo(hv[q]);
            f32x2 hi = fp8pk_hi(hv[q]);
            ax += w * lo.x; ay += w * lo.y; az += w * hi.x; aw += w * hi.y;
        }
    }
    for (; j + 3 < e; j += 4) {
        int u[4];
        #pragma unroll
        for (int q = 0; q < 4; ++q) u[q] = csr_src[j + q];
        float tt[4];
        #pragma unroll
        for (int q = 0; q < 4; ++q) tt[q] = el1[u[q] * 8 + h] + er;
        unsigned int hv[4];
        #pragma unroll
        for (int q = 0; q < 4; ++q) hv[q] = *(const unsigned int*)(feat8 + (size_t)u[q] * 256 + c0);
        #pragma unroll
        for (int q = 0; q < 4; ++q) {
            float tq = fmaxf(tt[q], NEG_SLOPE * tt[q]);
            float w = __expf(tq);
            wsum += w;
            f32x2 lo = fp8pk_lo(hv[q]);
            f32x2 hi = fp8pk_hi(hv[q]);
            ax += w * lo.x; ay += w * lo.y; az += w * hi.x; aw += w * hi.y;
        }
    }
    for (; j < e; ++j) {
        int u = csr_src[j];
        float tt = el1[u * 8 + h] + er;
        unsigned int hh = *(const unsigned int*)(feat8 + (size_t)u * 256 + c0);
        tt = fmaxf(tt, NEG_SLOPE * tt);
        float w = __expf(tt);
        wsum += w;
        f32x2 lo = fp8pk_lo(hh);
        f32x2 hi = fp8pk_hi(hh);
        ax += w * lo.x; ay += w * lo.y; az += w * hi.x; aw += w * hi.y;
    }
    float inv = (e > s) ? 1.f / wsum : 0.f;
    ushort4 rh = *(const ushort4*)(xb + (size_t)v * 256 + c0);
    float4 bb = *(const float4*)(b1 + c0);
    ushort4 o;
    o.x = f2bf(fmaxf(ax * inv + bf2f(rh.x) + bb.x, 0.f));
    o.y = f2bf(fmaxf(ay * inv + bf2f(rh.y) + bb.y, 0.f));
    o.z = f2bf(fmaxf(az * inv + bf2f(rh.z) + bb.z, 0.f));
    o.w = f2bf(fmaxf(aw * inv + bf2f(rh.w) + bb.w, 0.f));
    *(ushort4*)(y_b + (size_t)v * 256 + c0) = o;
}

// ---------------- GEMM2 + fused elr2: 64x64 blocks, prefetch pipeline ----------------

__global__ __launch_bounds__(256) void k_gemm2f(const unsigned short* __restrict__ Ab,
                                                const unsigned short* __restrict__ BT,  // [64][256]
                                                const float* __restrict__ al2, const float* __restrict__ ar2,
                                                unsigned short* __restrict__ feat2b, float* __restrict__ res2,
                                                float* __restrict__ el2, float* __restrict__ er2) {
    const int t = threadIdx.x;
    const int bm0 = blockIdx.x * 64;
    const int wave = t >> 6, lane = t & 63;
    const int wm = (wave & 1) * 32, wn = (wave >> 1) * 32;
    const int lm = lane & 15, quad = lane >> 4;

    f32x4 acc[2][2];
    #pragma unroll
    for (int i = 0; i < 2; ++i)
        #pragma unroll
        for (int j = 0; j < 2; ++j)
            #pragma unroll
            for (int r = 0; r < 4; ++r) acc[i][j][r] = 0.f;

    const unsigned short* bp[2];
    const unsigned short* ap[2];
    #pragma unroll
    for (int i = 0; i < 2; ++i) {
        bp[i] = BT + (size_t)(wn + i * 16 + lm) * 256 + quad * 8;
        ap[i] = Ab + (size_t)(bm0 + wm + i * 16 + lm) * 256 + quad * 8;
    }

    bf16x8 nb[2], na[2];
    #pragma unroll
    for (int i = 0; i < 2; ++i) { nb[i] = *(const bf16x8*)(bp[i]); na[i] = *(const bf16x8*)(ap[i]); }

    #pragma unroll
    for (int k0 = 0; k0 < 256; k0 += 32) {
        bf16x8 cb[2], ca[2];
        #pragma unroll
        for (int i = 0; i < 2; ++i) { cb[i] = nb[i]; ca[i] = na[i]; }
        if (k0 + 32 < 256) {
            #pragma unroll
            for (int i = 0; i < 2; ++i) {
                nb[i] = *(const bf16x8*)(bp[i] + k0 + 32);
                na[i] = *(const bf16x8*)(ap[i] + k0 + 32);
            }
        }
        #pragma unroll
        for (int mi = 0; mi < 2; ++mi)
            #pragma unroll
            for (int ni = 0; ni < 2; ++ni)
                acc[mi][ni] = __builtin_amdgcn_mfma_f32_16x16x32_bf16(ca[mi], cb[ni], acc[mi][ni], 0, 0, 0);
    }

    #pragma unroll
    for (int mi = 0; mi < 2; ++mi) {
        #pragma unroll
        for (int ni = 0; ni < 2; ++ni) {
            int col = wn + ni * 16 + lm;  // 0..63
            #pragma unroll
            for (int r = 0; r < 4; ++r) {
                int row = bm0 + wm + mi * 16 + quad * 4 + r;
                float val = acc[mi][ni][r];
                if (col < 32) feat2b[(size_t)row * 32 + col] = f2bf(val);
                else          res2[(size_t)row * 32 + col - 32] = val;
            }
        }
    }
    if (wn == 0) {
        float alv[2], arv[2];
        #pragma unroll
        for (int ni = 0; ni < 2; ++ni) {
            alv[ni] = al2[ni * 16 + lm];
            arv[ni] = ar2[ni * 16 + lm];
        }
        #pragma unroll
        for (int mi = 0; mi < 2; ++mi) {
            #pragma unroll
            for (int r = 0; r < 4; ++r) {
                float pel = acc[mi][0][r] * alv[0] + acc[mi][1][r] * alv[1];
                float per = acc[mi][0][r] * arv[0] + acc[mi][1][r] * arv[1];
                #pragma unroll
                for (int m = 1; m <= 8; m <<= 1) {
                    pel += __shfl_xor(pel, m, 64);
                    per += __shfl_xor(per, m, 64);
                }
                if (lm == 0) {
                    int row = bm0 + wm + mi * 16 + quad * 4 + r;
                    el2[row] = pel;
                    er2[row] = per;
                }
            }
        }
    }
}

// ---------------- L2 aggregation ----------------

__global__ __launch_bounds__(256) void k_agg2(const unsigned short* __restrict__ feat2b,
                                              const float* __restrict__ el2, const float* __restrict__ er2,
                                              const float* __restrict__ res2, const float* __restrict__ b2,
                                              const int* __restrict__ rowoff, const int* __restrict__ csr_src,
                                              float* __restrict__ out) {
    int g = blockIdx.x * 256 + threadIdx.x;
    int v = g >> 5;
    int c = g & 31;
    if (v >= N_NODES) return;
    float er = er2[v];
    float acc = 0.f, wsum = 0.f;
    int s = rowoff[v], e = rowoff[v + 1];
    int j = s;
    for (; j + 3 < e; j += 4) {
        int u[4];
        #pragma unroll
        for (int q = 0; q < 4; ++q) u[q] = csr_src[j + q];
        float tt[4];
        #pragma unroll
        for (int q = 0; q < 4; ++q) tt[q] = el2[u[q]] + er;
        unsigned short fv[4];
        #pragma unroll
        for (int q = 0; q < 4; ++q) fv[q] = feat2b[(size_t)u[q] * 32 + c];
        #pragma unroll
        for (int q = 0; q < 4; ++q) {
            float tq = fmaxf(tt[q], NEG_SLOPE * tt[q]);
            float w = __expf(tq);
            wsum += w;
            acc += w * bf2f(fv[q]);
        }
    }
    for (; j < e; ++j) {
        int u = csr_src[j];
        float t = el2[u] + er;
        t = fmaxf(t, NEG_SLOPE * t);
        float w = __expf(t);
        wsum += w;
        acc += w * bf2f(feat2b[(size_t)u * 32 + c]);
    }
    float inv = (e > s) ? 1.f / wsum : 0.f;
    out[(size_t)v * 32 + c] = acc * inv + res2[(size_t)v * 32 + c] + b2[c];
}

// ---------------- launch ----------------

extern "C" void kernel_launch(void* const* d_in, const int* in_sizes, int n_in,
                              void* d_out, int out_size, void* d_ws, size_t ws_size,
                              hipStream_t stream) {
    const float* x     = (const float*)d_in[0];
    const int*   src   = (const int*)d_in[1];
    const int*   dst   = (const int*)d_in[2];
    const float* W1    = (const float*)d_in[3];
    const float* al1   = (const float*)d_in[4];
    const float* ar1   = (const float*)d_in[5];
    const float* b1    = (const float*)d_in[6];
    const float* W2    = (const float*)d_in[7];
    const float* al2   = (const float*)d_in[8];
    const float* ar2   = (const float*)d_in[9];
    const float* resW2 = (const float*)d_in[10];
    const float* b2    = (const float*)d_in[11];
    float* out = (float*)d_out;

    char* ws = (char*)d_ws;
    size_t off = 0;
    auto alloc = [&](size_t bytes) {
        void* p = ws + off;
        off += (bytes + 255) & ~(size_t)255;
        return p;
    };
    unsigned short* xb     = (unsigned short*)alloc((size_t)M_PAD * 256 * 2);
    unsigned char*  feat8  = (unsigned char*)alloc((size_t)M_PAD * 256);
    unsigned short* y_b    = (unsigned short*)alloc((size_t)M_PAD * 256 * 2);
    unsigned short* W1F    = (unsigned short*)alloc((size_t)256 * 256 * 2);
    unsigned short* W2T    = (unsigned short*)alloc((size_t)64 * 256 * 2);
    unsigned short* feat2b = (unsigned short*)alloc((size_t)M_PAD * 32 * 2);
    float* res2   = (float*)alloc((size_t)M_PAD * 32 * 4);
    float* el1    = (float*)alloc((size_t)M_PAD * 8 * 4);
    float* er1    = (float*)alloc((size_t)M_PAD * 8 * 4);
    float* el2    = (float*)alloc((size_t)M_PAD * 4);
    float* er2    = (float*)alloc((size_t)M_PAD * 4);
    int*   rowoff = (int*)alloc((size_t)(N_NODES + 1) * 4);
    int*   csr    = (int*)alloc((size_t)N_EDGES * 4);
    uint2* seg    = (uint2*)alloc((size_t)NBUCK * BKA * SEGCAP * 8);
    unsigned int* cnt  = (unsigned int*)alloc((size_t)BKA * NBUCK * 4);
    unsigned int* btot = (unsigned int*)alloc((size_t)NBUCK * 4);
    (void)ws_size;

    // trans: W1 -> fragment-major W1F, W2/resW2 row-major W2T, xb cast, btot zero
    k_trans<<<dim3(10, 80), 256, 0, stream>>>(W1, W2, resW2, x, W1F, W2T, xb, btot);

    // CSR build phase A (standalone)
    k_bucketA<<<BKA, 256, 0, stream>>>(src, dst, seg, cnt, btot);

    // GEMM1: coalesced operands (A LDS-staged, B fragment-major)
    k_gemm1<<<GBLK, 512, 0, stream>>>(xb, W1F, al1, ar1, feat8, el1, er1);

    // CSR build phase B (standalone)
    k_bucketB<<<NBUCK, 256, 0, stream>>>(seg, cnt, btot, rowoff, csr);

    // Layer 1 aggregation
    k_agg1<<<(M_PAD * 64) / 256, 256, 0, stream>>>(feat8, el1, er1, xb, b1, rowoff, csr, y_b);

    // Layer 2
    k_gemm2f<<<M_PAD / 64, 256, 0, stream>>>(y_b, W2T, al2, ar2, feat2b, res2, el2, er2);
    k_agg2<<<(N_NODES * 32) / 256, 256, 0, stream>>>(feat2b, el2, er2, res2, b2, rowoff, csr, out);
}

// Round 12
// 245.843 us; speedup vs baseline: 1.1341x; 1.0210x over previous
//
#include <hip/hip_runtime.h>
#include <hip/hip_bf16.h>
#include <hip/hip_fp8.h>

#define N_NODES 50000
#define M_PAD   50048          // 782 * 64
#define N_EDGES 800000
#define NEG_SLOPE 0.2f

#define EPT 8                                            // edges per thread (bucketA, 256 thr)
#define BKA 391                                          // ceil(800000 / (256*8)) bucketA blocks
#define NBUCK 256                                        // dst buckets
#define NPB 196                                          // nodes per bucket (256*196 = 50176 >= 50000)
#define SEGCAP 40                                        // per-(block,bucket) segment capacity
#define GBLK 782                                         // GEMM1 blocks (64 rows x 256 cols, 512 thr)
#define APAD 264                                         // sA row stride in shorts (512B + 16B pad)
#define FUSE1_T (800 + BKA)                              // 1191
#define FUSE2_T (GBLK + NBUCK)                           // 1038

typedef __attribute__((ext_vector_type(8))) short bf16x8;
typedef __attribute__((ext_vector_type(4))) float f32x4;
typedef __attribute__((ext_vector_type(2))) float f32x2;

__device__ __forceinline__ unsigned short f2bf(float f) {
    unsigned u = __float_as_uint(f);
    u += 0x7FFFu + ((u >> 16) & 1u);          // RNE
    return (unsigned short)(u >> 16);
}
__device__ __forceinline__ float bf2f(unsigned short h) {
    return __uint_as_float(((unsigned)h) << 16);
}

// ---- fp8 e4m3 HW converts (gfx950 OCP) ----
#if __has_builtin(__builtin_amdgcn_cvt_pk_f32_fp8)
__device__ __forceinline__ f32x2 fp8pk_lo(unsigned int p) { return __builtin_amdgcn_cvt_pk_f32_fp8(p, false); }
__device__ __forceinline__ f32x2 fp8pk_hi(unsigned int p) { return __builtin_amdgcn_cvt_pk_f32_fp8(p, true); }
#else
__device__ __forceinline__ float fp82f_s(unsigned char b) {
    __hip_fp8_e4m3 t; t.__x = (__hip_fp8_storage_t)b; return (float)t;
}
__device__ __forceinline__ f32x2 fp8pk_lo(unsigned int p) {
    f32x2 r; r.x = fp82f_s(p & 0xff); r.y = fp82f_s((p >> 8) & 0xff); return r;
}
__device__ __forceinline__ f32x2 fp8pk_hi(unsigned int p) {
    f32x2 r; r.x = fp82f_s((p >> 16) & 0xff); r.y = fp82f_s(p >> 24); return r;
}
#endif

#if __has_builtin(__builtin_amdgcn_cvt_pk_fp8_f32)
__device__ __forceinline__ unsigned int fp8enc2(float a, float b) {
    return (unsigned int)__builtin_amdgcn_cvt_pk_fp8_f32(a, b, 0, false);
}
#else
__device__ __forceinline__ unsigned int fp8enc2(float a, float b) {
    __hip_fp8_e4m3 ta(a), tb(b);
    return (unsigned int)ta.__x | ((unsigned int)tb.__x << 8);
}
#endif

// ---------------- FUSE1: trans roles (0..799) || bucketA roles (800..1190), 256 thr ----------------

__global__ __launch_bounds__(256) void k_fuse1(const float* __restrict__ W1, const float* __restrict__ W2,
                                               const float* __restrict__ resW2, const float* __restrict__ x,
                                               const int* __restrict__ src, const int* __restrict__ dst,
                                               unsigned short* __restrict__ W1F, unsigned short* __restrict__ W2T,
                                               unsigned short* __restrict__ xb,
                                               uint2* __restrict__ seg, unsigned int* __restrict__ cnt,
                                               unsigned int* __restrict__ btot) {
    int bid = blockIdx.x;
    if (bid >= 800) {
        // ---- bucketA role (byte-identical body; vb = bid - 800) ----
        __shared__ unsigned int lcnt[NBUCK];
        int vb = bid - 800;
        lcnt[threadIdx.x] = 0;
        __syncthreads();
        int base = vb * (256 * EPT) + threadIdx.x;
        int sv[EPT], dv[EPT], bk[EPT], lr[EPT];
        #pragma unroll
        for (int q = 0; q < EPT; ++q) {
            int i = base + q * 256;
            if (i < N_EDGES) { sv[q] = src[i]; dv[q] = dst[i]; }
            else dv[q] = -1;
        }
        #pragma unroll
        for (int q = 0; q < EPT; ++q) {
            if (dv[q] >= 0) {
                bk[q] = (int)((unsigned)dv[q] / NPB);
                lr[q] = atomicAdd(&lcnt[bk[q]], 1u);
            }
        }
        __syncthreads();
        cnt[vb * NBUCK + threadIdx.x] = lcnt[threadIdx.x];
        if (lcnt[threadIdx.x] > 0) atomicAdd(&btot[threadIdx.x], lcnt[threadIdx.x]);
        #pragma unroll
        for (int q = 0; q < EPT; ++q) {
            if (dv[q] >= 0 && lr[q] < SEGCAP) {
                size_t slot = ((size_t)bk[q] * BKA + vb) * SEGCAP + lr[q];
                seg[slot] = make_uint2((unsigned)sv[q], (unsigned)dv[q] - (unsigned)bk[q] * NPB);
            }
        }
        return;
    }
    int flat = bid;                               // 0..799 (1D-flattened trans roles)
    if (flat < 80) {
        // W transpose role: bx = flat%10, k0 = (flat/10)*32
        __shared__ unsigned short tile[32][33];
        int bx = flat % 10;
        const float* in;
        int Nn, n0;
        if (bx < 8)      { in = W1;    Nn = 256; n0 = bx * 32; }
        else if (bx == 8){ in = W2;    Nn = 32;  n0 = 0; }
        else             { in = resW2; Nn = 32;  n0 = 0; }
        int k0 = (flat / 10) * 32;
        int tx = threadIdx.x & 31, ty = threadIdx.x >> 5;
        #pragma unroll
        for (int r = 0; r < 4; ++r) {
            int k = k0 + ty + r * 8;
            tile[ty + r * 8][tx] = f2bf(in[(size_t)k * Nn + n0 + tx]);
        }
        __syncthreads();
        #pragma unroll
        for (int r = 0; r < 4; ++r) {
            int n = ty + r * 8;
            unsigned short val = tile[tx][n];
            int col = n0 + n;
            int kk = k0 + tx;
            if (bx < 8) {
                // fragment-major W1F (verified round 11)
                size_t idx = (((size_t)(col >> 4) * 8 + (kk >> 5)) << 9)
                           + ((((kk >> 3) & 3) * 16 + (col & 15)) << 3) + (kk & 7);
                W1F[idx] = val;
            } else {
                unsigned short* out = (bx == 8) ? W2T : (W2T + 32 * 256);
                out[(size_t)col * 256 + kk] = val;
            }
        }
    } else {
        int xid = flat - 80;                      // 0..719
        const size_t NCHUNK = (size_t)M_PAD * 256 / 8;
        for (size_t c = (size_t)xid * 256 + threadIdx.x; c < NCHUNK; c += (size_t)720 * 256) {
            size_t base = c * 8;
            float4 a = make_float4(0.f, 0.f, 0.f, 0.f), b = a;
            if (base < (size_t)N_NODES * 256) {
                a = *(const float4*)(x + base);
                b = *(const float4*)(x + base + 4);
            }
            ushort4 h0, h1;
            h0.x = f2bf(a.x); h0.y = f2bf(a.y); h0.z = f2bf(a.z); h0.w = f2bf(a.w);
            h1.x = f2bf(b.x); h1.y = f2bf(b.y); h1.z = f2bf(b.z); h1.w = f2bf(b.w);
            *(ushort4*)(xb + base) = h0;
            *(ushort4*)(xb + base + 4) = h1;
        }
    }
}

// ---------------- GEMM1 body (verified round 11: A LDS-staged, B fragment-major) ----------------

__device__ __forceinline__ void gemm1_body(int gblk,
                                           const unsigned short* __restrict__ xb,
                                           const unsigned short* __restrict__ W1F,
                                           const float* __restrict__ al1, const float* __restrict__ ar1,
                                           unsigned char* __restrict__ Cb8,
                                           float* __restrict__ el1, float* __restrict__ er1) {
    __shared__ unsigned short sA[64 * APAD];   // 33.8 KB
    const int t = threadIdx.x;
    const int bm0 = gblk * 64;
    const int wave = t >> 6, lane = t & 63;
    const int wm = (wave & 1) * 32, wn = (wave >> 1) * 64;
    const int lm = lane & 15, quad = lane >> 4;

    #pragma unroll
    for (int rr = 0; rr < 4; ++rr) {
        int ch = rr * 512 + t;                 // 0..2047
        int row = ch >> 5, w = ch & 31;
        bf16x8 vv = *(const bf16x8*)(xb + (size_t)(bm0 + row) * 256 + w * 8);
        *(bf16x8*)(sA + row * APAD + w * 8) = vv;
    }
    __syncthreads();

    f32x4 acc[2][4];
    #pragma unroll
    for (int i = 0; i < 2; ++i)
        #pragma unroll
        for (int j = 0; j < 4; ++j)
            #pragma unroll
            for (int r = 0; r < 4; ++r) acc[i][j][r] = 0.f;

    const unsigned short* bp[4];
    #pragma unroll
    for (int i = 0; i < 4; ++i)
        bp[i] = W1F + ((size_t)((wave >> 1) * 4 + i)) * 4096 + lane * 8;
    const unsigned short* ap[2];
    #pragma unroll
    for (int i = 0; i < 2; ++i)
        ap[i] = sA + (wm + i * 16 + lm) * APAD + quad * 8;

    bf16x8 nb[4];
    #pragma unroll
    for (int i = 0; i < 4; ++i) nb[i] = *(const bf16x8*)(bp[i]);

    #pragma unroll
    for (int q = 0; q < 8; ++q) {
        bf16x8 cb[4];
        #pragma unroll
        for (int i = 0; i < 4; ++i) cb[i] = nb[i];
        if (q < 7) {
            #pragma unroll
            for (int i = 0; i < 4; ++i) nb[i] = *(const bf16x8*)(bp[i] + (q + 1) * 512);
        }
        bf16x8 ca[2];
        #pragma unroll
        for (int i = 0; i < 2; ++i) ca[i] = *(const bf16x8*)(ap[i] + q * 32);
        #pragma unroll
        for (int mi = 0; mi < 2; ++mi)
            #pragma unroll
            for (int ni = 0; ni < 4; ++ni)
                acc[mi][ni] = __builtin_amdgcn_mfma_f32_16x16x32_bf16(ca[mi], cb[ni], acc[mi][ni], 0, 0, 0);
    }

    #pragma unroll
    for (int mi = 0; mi < 2; ++mi) {
        #pragma unroll
        for (int ni = 0; ni < 4; ++ni) {
            int col = wn + ni * 16 + lm;
            int row0 = bm0 + wm + mi * 16 + quad * 4;
            unsigned int p01 = fp8enc2(acc[mi][ni][0], acc[mi][ni][1]);
            unsigned int p23 = fp8enc2(acc[mi][ni][2], acc[mi][ni][3]);
            Cb8[(size_t)(row0 + 0) * 256 + col] = (unsigned char)(p01 & 0xff);
            Cb8[(size_t)(row0 + 1) * 256 + col] = (unsigned char)((p01 >> 8) & 0xff);
            Cb8[(size_t)(row0 + 2) * 256 + col] = (unsigned char)(p23 & 0xff);
            Cb8[(size_t)(row0 + 3) * 256 + col] = (unsigned char)((p23 >> 8) & 0xff);
        }
    }
    float alv[4], arv[4];
    #pragma unroll
    for (int ni = 0; ni < 4; ++ni) {
        int colg = wn + ni * 16 + lm;
        alv[ni] = al1[colg];
        arv[ni] = ar1[colg];
    }
    int head0 = wn >> 5;
    #pragma unroll
    for (int gg = 0; gg < 2; ++gg) {
        #pragma unroll
        for (int mi = 0; mi < 2; ++mi) {
            #pragma unroll
            for (int r = 0; r < 4; ++r) {
                float pel = acc[mi][2 * gg][r] * alv[2 * gg] + acc[mi][2 * gg + 1][r] * alv[2 * gg + 1];
                float per = acc[mi][2 * gg][r] * arv[2 * gg] + acc[mi][2 * gg + 1][r] * arv[2 * gg + 1];
                #pragma unroll
                for (int m = 1; m <= 8; m <<= 1) {
                    pel += __shfl_xor(pel, m, 64);
                    per += __shfl_xor(per, m, 64);
                }
                if (lm == 0) {
                    int row = bm0 + wm + mi * 16 + quad * 4 + r;
                    el1[row * 8 + head0 + gg] = pel;
                    er1[row * 8 + head0 + gg] = per;
                }
            }
        }
    }
}

// ---------------- FUSE2: gemm1 roles (0..781) || bucketB roles (782..1037), 512 thr ----------------

__global__ __launch_bounds__(512) void k_fuse2(const unsigned short* __restrict__ xb,
                                               const unsigned short* __restrict__ W1F,
                                               const float* __restrict__ al1, const float* __restrict__ ar1,
                                               unsigned char* __restrict__ Cb8,
                                               float* __restrict__ el1, float* __restrict__ er1,
                                               const uint2* __restrict__ seg, const unsigned int* __restrict__ cnt,
                                               const unsigned int* __restrict__ btot,
                                               int* __restrict__ rowoff, int* __restrict__ csr_src) {
    int bid = blockIdx.x;
    if (bid < GBLK) {
        gemm1_body(bid, xb, W1F, al1, ar1, Cb8, el1, er1);
        return;
    }
    // ---- bucketB role, ported to 512 threads (scan sections guarded t<256) ----
    __shared__ unsigned int hist[NPB];
    __shared__ unsigned int cursor[NPB];
    __shared__ unsigned int red[256];
    int b = bid - GBLK;
    int t = threadIdx.x;
    if (t < NPB) hist[t] = 0;
    if (t < 256) red[t] = (t < b) ? btot[t] : 0;
    __syncthreads();
    #pragma unroll
    for (int off = 128; off > 0; off >>= 1) {
        if (t < off) red[t] += red[t + off];
        __syncthreads();
    }
    unsigned int base = red[0];
    __syncthreads();
    // pass 1: count (stride 512)
    for (int s = t; s < BKA; s += 512) {
        unsigned int c = cnt[s * NBUCK + b];
        const uint2* sp = seg + ((size_t)b * BKA + s) * SEGCAP;
        for (unsigned int j = 0; j < c; ++j) {
            atomicAdd(&hist[sp[j].y], 1u);
        }
    }
    __syncthreads();
    // exclusive scan of hist[NPB] via Hillis-Steele in red[] (t<256 active)
    if (t < 256) red[t] = (t < NPB) ? hist[t] : 0;
    __syncthreads();
    for (int off = 1; off < 256; off <<= 1) {
        unsigned int val = (t >= off && t < 256) ? red[t - off] : 0u;
        __syncthreads();
        if (t < 256) red[t] += val;
        __syncthreads();
    }
    if (t < NPB) {
        unsigned int excl = red[t] - hist[t];
        cursor[t] = excl;
        int v = b * NPB + t;
        if (v < N_NODES) rowoff[v] = (int)(base + excl);
    }
    if (b == NBUCK - 1 && t == 0) rowoff[N_NODES] = N_EDGES;
    __syncthreads();
    // pass 2: place (stride 512)
    for (int s = t; s < BKA; s += 512) {
        unsigned int c = cnt[s * NBUCK + b];
        const uint2* sp = seg + ((size_t)b * BKA + s) * SEGCAP;
        for (unsigned int j = 0; j < c; ++j) {
            uint2 eg = sp[j];
            unsigned int r = atomicAdd(&cursor[eg.y], 1u);
            csr_src[base + r] = (int)eg.x;
        }
    }
}

// ---------------- L1 aggregation: one wave per dst node, shuffle-shared softmax weights ----------------

__global__ __launch_bounds__(256) void k_agg1(const unsigned char* __restrict__ feat8,
                                              const float* __restrict__ el1, const float* __restrict__ er1,
                                              const unsigned short* __restrict__ xb, const float* __restrict__ b1,
                                              const int* __restrict__ rowoff, const int* __restrict__ csr_src,
                                              unsigned short* __restrict__ y_b) {
    int v = (blockIdx.x * 256 + threadIdx.x) >> 6;
    int lane = threadIdx.x & 63;
    if (v >= M_PAD) return;
    int c0 = lane * 4;
    if (v >= N_NODES) {
        ushort4 z = {0, 0, 0, 0};
        *(ushort4*)(y_b + (size_t)v * 256 + c0) = z;
        return;
    }
    int h = lane >> 3;
    float er  = er1[v * 8 + h];
    float erc = er1[v * 8 + (lane & 7)];
    float ax = 0.f, ay = 0.f, az = 0.f, aw = 0.f, wsum = 0.f;
    int s = rowoff[v], e = rowoff[v + 1];
    int j = s;
    for (; j + 7 < e; j += 8) {
        int um = csr_src[j + (lane >> 3)];
        float elv = el1[um * 8 + (lane & 7)];
        int u[8];
        #pragma unroll
        for (int q = 0; q < 8; ++q) u[q] = __shfl(um, q * 8);
        unsigned int hv[8];
        #pragma unroll
        for (int q = 0; q < 8; ++q) hv[q] = *(const unsigned int*)(feat8 + (size_t)u[q] * 256 + c0);
        float tq = elv + erc;
        tq = fmaxf(tq, NEG_SLOPE * tq);
        float wv = __expf(tq);
        #pragma unroll
        for (int q = 0; q < 8; ++q) {
            float w = __shfl(wv, q * 8 + h);
            wsum += w;
            f32x2 lo = fp8pk_lo(hv[q]);
            f32x2 hi = fp8pk_hi(hv[q]);
            ax += w * lo.x; ay += w * lo.y; az += w * hi.x; aw += w * hi.y;
        }
    }
    for (; j + 3 < e; j += 4) {
        int u[4];
        #pragma unroll
        for (int q = 0; q < 4; ++q) u[q] = csr_src[j + q];
        float tt[4];
        #pragma unroll
        for (int q = 0; q < 4; ++q) tt[q] = el1[u[q] * 8 + h] + er;
        unsigned int hv[4];
        #pragma unroll
        for (int q = 0; q < 4; ++q) hv[q] = *(const unsigned int*)(feat8 + (size_t)u[q] * 256 + c0);
        #pragma unroll
        for (int q = 0; q < 4; ++q) {
            float tq = fmaxf(tt[q], NEG_SLOPE * tt[q]);
            float w = __expf(tq);
            wsum += w;
            f32x2 lo = fp8pk_lo(hv[q]);
            f32x2 hi = fp8pk_hi(hv[q]);
            ax += w * lo.x; ay += w * lo.y; az += w * hi.x; aw += w * hi.y;
        }
    }
    for (; j < e; ++j) {
        int u = csr_src[j];
        float tt = el1[u * 8 + h] + er;
        unsigned int hh = *(const unsigned int*)(feat8 + (size_t)u * 256 + c0);
        tt = fmaxf(tt, NEG_SLOPE * tt);
        float w = __expf(tt);
        wsum += w;
        f32x2 lo = fp8pk_lo(hh);
        f32x2 hi = fp8pk_hi(hh);
        ax += w * lo.x; ay += w * lo.y; az += w * hi.x; aw += w * hi.y;
    }
    float inv = (e > s) ? 1.f / wsum : 0.f;
    ushort4 rh = *(const ushort4*)(xb + (size_t)v * 256 + c0);
    float4 bb = *(const float4*)(b1 + c0);
    ushort4 o;
    o.x = f2bf(fmaxf(ax * inv + bf2f(rh.x) + bb.x, 0.f));
    o.y = f2bf(fmaxf(ay * inv + bf2f(rh.y) + bb.y, 0.f));
    o.z = f2bf(fmaxf(az * inv + bf2f(rh.z) + bb.z, 0.f));
    o.w = f2bf(fmaxf(aw * inv + bf2f(rh.w) + bb.w, 0.f));
    *(ushort4*)(y_b + (size_t)v * 256 + c0) = o;
}

// ---------------- GEMM2 + fused elr2: 64x64 blocks, prefetch pipeline ----------------

__global__ __launch_bounds__(256) void k_gemm2f(const unsigned short* __restrict__ Ab,
                                                const unsigned short* __restrict__ BT,  // [64][256]
                                                const float* __restrict__ al2, const float* __restrict__ ar2,
                                                unsigned short* __restrict__ feat2b, float* __restrict__ res2,
                                                float* __restrict__ el2, float* __restrict__ er2) {
    const int t = threadIdx.x;
    const int bm0 = blockIdx.x * 64;
    const int wave = t >> 6, lane = t & 63;
    const int wm = (wave & 1) * 32, wn = (wave >> 1) * 32;
    const int lm = lane & 15, quad = lane >> 4;

    f32x4 acc[2][2];
    #pragma unroll
    for (int i = 0; i < 2; ++i)
        #pragma unroll
        for (int j = 0; j < 2; ++j)
            #pragma unroll
            for (int r = 0; r < 4; ++r) acc[i][j][r] = 0.f;

    const unsigned short* bp[2];
    const unsigned short* ap[2];
    #pragma unroll
    for (int i = 0; i < 2; ++i) {
        bp[i] = BT + (size_t)(wn + i * 16 + lm) * 256 + quad * 8;
        ap[i] = Ab + (size_t)(bm0 + wm + i * 16 + lm) * 256 + quad * 8;
    }

    bf16x8 nb[2], na[2];
    #pragma unroll
    for (int i = 0; i < 2; ++i) { nb[i] = *(const bf16x8*)(bp[i]); na[i] = *(const bf16x8*)(ap[i]); }

    #pragma unroll
    for (int k0 = 0; k0 < 256; k0 += 32) {
        bf16x8 cb[2], ca[2];
        #pragma unroll
        for (int i = 0; i < 2; ++i) { cb[i] = nb[i]; ca[i] = na[i]; }
        if (k0 + 32 < 256) {
            #pragma unroll
            for (int i = 0; i < 2; ++i) {
                nb[i] = *(const bf16x8*)(bp[i] + k0 + 32);
                na[i] = *(const bf16x8*)(ap[i] + k0 + 32);
            }
        }
        #pragma unroll
        for (int mi = 0; mi < 2; ++mi)
            #pragma unroll
            for (int ni = 0; ni < 2; ++ni)
                acc[mi][ni] = __builtin_amdgcn_mfma_f32_16x16x32_bf16(ca[mi], cb[ni], acc[mi][ni], 0, 0, 0);
    }

    #pragma unroll
    for (int mi = 0; mi < 2; ++mi) {
        #pragma unroll
        for (int ni = 0; ni < 2; ++ni) {
            int col = wn + ni * 16 + lm;  // 0..63
            #pragma unroll
            for (int r = 0; r < 4; ++r) {
                int row = bm0 + wm + mi * 16 + quad * 4 + r;
                float val = acc[mi][ni][r];
                if (col < 32) feat2b[(size_t)row * 32 + col] = f2bf(val);
                else          res2[(size_t)row * 32 + col - 32] = val;
            }
        }
    }
    if (wn == 0) {
        float alv[2], arv[2];
        #pragma unroll
        for (int ni = 0; ni < 2; ++ni) {
            alv[ni] = al2[ni * 16 + lm];
            arv[ni] = ar2[ni * 16 + lm];
        }
        #pragma unroll
        for (int mi = 0; mi < 2; ++mi) {
            #pragma unroll
            for (int r = 0; r < 4; ++r) {
                float pel = acc[mi][0][r] * alv[0] + acc[mi][1][r] * alv[1];
                float per = acc[mi][0][r] * arv[0] + acc[mi][1][r] * arv[1];
                #pragma unroll
                for (int m = 1; m <= 8; m <<= 1) {
                    pel += __shfl_xor(pel, m, 64);
                    per += __shfl_xor(per, m, 64);
                }
                if (lm == 0) {
                    int row = bm0 + wm + mi * 16 + quad * 4 + r;
                    el2[row] = pel;
                    er2[row] = per;
                }
            }
        }
    }
}

// ---------------- L2 aggregation ----------------

__global__ __launch_bounds__(256) void k_agg2(const unsigned short* __restrict__ feat2b,
                                              const float* __restrict__ el2, const float* __restrict__ er2,
                                              const float* __restrict__ res2, const float* __restrict__ b2,
                                              const int* __restrict__ rowoff, const int* __restrict__ csr_src,
                                              float* __restrict__ out) {
    int g = blockIdx.x * 256 + threadIdx.x;
    int v = g >> 5;
    int c = g & 31;
    if (v >= N_NODES) return;
    float er = er2[v];
    float acc = 0.f, wsum = 0.f;
    int s = rowoff[v], e = rowoff[v + 1];
    int j = s;
    for (; j + 3 < e; j += 4) {
        int u[4];
        #pragma unroll
        for (int q = 0; q < 4; ++q) u[q] = csr_src[j + q];
        float tt[4];
        #pragma unroll
        for (int q = 0; q < 4; ++q) tt[q] = el2[u[q]] + er;
        unsigned short fv[4];
        #pragma unroll
        for (int q = 0; q < 4; ++q) fv[q] = feat2b[(size_t)u[q] * 32 + c];
        #pragma unroll
        for (int q = 0; q < 4; ++q) {
            float tq = fmaxf(tt[q], NEG_SLOPE * tt[q]);
            float w = __expf(tq);
            wsum += w;
            acc += w * bf2f(fv[q]);
        }
    }
    for (; j < e; ++j) {
        int u = csr_src[j];
        float t = el2[u] + er;
        t = fmaxf(t, NEG_SLOPE * t);
        float w = __expf(t);
        wsum += w;
        acc += w * bf2f(feat2b[(size_t)u * 32 + c]);
    }
    float inv = (e > s) ? 1.f / wsum : 0.f;
    out[(size_t)v * 32 + c] = acc * inv + res2[(size_t)v * 32 + c] + b2[c];
}

// ---------------- launch ----------------

extern "C" void kernel_launch(void* const* d_in, const int* in_sizes, int n_in,
                              void* d_out, int out_size, void* d_ws, size_t ws_size,
                              hipStream_t stream) {
    const float* x     = (const float*)d_in[0];
    const int*   src   = (const int*)d_in[1];
    const int*   dst   = (const int*)d_in[2];
    const float* W1    = (const float*)d_in[3];
    const float* al1   = (const float*)d_in[4];
    const float* ar1   = (const float*)d_in[5];
    const float* b1    = (const float*)d_in[6];
    const float* W2    = (const float*)d_in[7];
    const float* al2   = (const float*)d_in[8];
    const float* ar2   = (const float*)d_in[9];
    const float* resW2 = (const float*)d_in[10];
    const float* b2    = (const float*)d_in[11];
    float* out = (float*)d_out;

    char* ws = (char*)d_ws;
    size_t off = 0;
    auto alloc = [&](size_t bytes) {
        void* p = ws + off;
        off += (bytes + 255) & ~(size_t)255;
        return p;
    };
    unsigned short* xb     = (unsigned short*)alloc((size_t)M_PAD * 256 * 2);
    unsigned char*  feat8  = (unsigned char*)alloc((size_t)M_PAD * 256);
    unsigned short* y_b    = (unsigned short*)alloc((size_t)M_PAD * 256 * 2);
    unsigned short* W1F    = (unsigned short*)alloc((size_t)256 * 256 * 2);
    unsigned short* W2T    = (unsigned short*)alloc((size_t)64 * 256 * 2);
    unsigned short* feat2b = (unsigned short*)alloc((size_t)M_PAD * 32 * 2);
    float* res2   = (float*)alloc((size_t)M_PAD * 32 * 4);
    float* el1    = (float*)alloc((size_t)M_PAD * 8 * 4);
    float* er1    = (float*)alloc((size_t)M_PAD * 8 * 4);
    float* el2    = (float*)alloc((size_t)M_PAD * 4);
    float* er2    = (float*)alloc((size_t)M_PAD * 4);
    int*   rowoff = (int*)alloc((size_t)(N_NODES + 1) * 4);
    int*   csr    = (int*)alloc((size_t)N_EDGES * 4);
    uint2* seg    = (uint2*)alloc((size_t)NBUCK * BKA * SEGCAP * 8);
    unsigned int* cnt  = (unsigned int*)alloc((size_t)BKA * NBUCK * 4);
    unsigned int* btot = (unsigned int*)alloc((size_t)NBUCK * 4);
    (void)ws_size;

    // btot zero (graph-capturable)
    hipMemsetAsync(btot, 0, (size_t)NBUCK * 4, stream);

    // FUSE1: trans || bucketA
    k_fuse1<<<FUSE1_T, 256, 0, stream>>>(W1, W2, resW2, x, src, dst, W1F, W2T, xb, seg, cnt, btot);

    // FUSE2: gemm1 || bucketB
    k_fuse2<<<FUSE2_T, 512, 0, stream>>>(xb, W1F, al1, ar1, feat8, el1, er1, seg, cnt, btot, rowoff, csr);

    // Layer 1 aggregation
    k_agg1<<<(M_PAD * 64) / 256, 256, 0, stream>>>(feat8, el1, er1, xb, b1, rowoff, csr, y_b);

    // Layer 2
    k_gemm2f<<<M_PAD / 64, 256, 0, stream>>>(y_b, W2T, al2, ar2, feat2b, res2, el2, er2);
    k_agg2<<<(N_NODES * 32) / 256, 256, 0, stream>>>(feat2b, el2, er2, res2, b2, rowoff, csr, out);
}

// Round 14
// 236.253 us; speedup vs baseline: 1.1801x; 1.0406x over previous
//
#include <hip/hip_runtime.h>
#include <hip/hip_bf16.h>
#include <hip/hip_fp8.h>

#define N_NODES 50000
#define M_PAD   50048          // 782 * 64
#define N_EDGES 800000
#define NEG_SLOPE 0.2f

#define EPT 8                                            // edges per thread (bucketA, 256 thr)
#define BKA 391                                          // ceil(800000 / (256*8)) bucketA blocks
#define NBUCK 256                                        // dst buckets
#define NPB 196                                          // nodes per bucket (256*196 = 50176 >= 50000)
#define SEGCAP 40                                        // per-(block,bucket) segment capacity
#define GBLK 782                                         // GEMM1 blocks (64 rows x 256 cols, 512 thr)
#define APAD 264                                         // sA row stride in shorts (512B + 16B pad)
#define FUSE1_T (800 + BKA)                              // 1191
#define FUSE2_T (GBLK + NBUCK)                           // 1038

typedef __attribute__((ext_vector_type(8))) short bf16x8;
typedef __attribute__((ext_vector_type(4))) float f32x4;
typedef __attribute__((ext_vector_type(2))) float f32x2;

__device__ __forceinline__ unsigned short f2bf(float f) {
    unsigned u = __float_as_uint(f);
    u += 0x7FFFu + ((u >> 16) & 1u);          // RNE
    return (unsigned short)(u >> 16);
}
__device__ __forceinline__ float bf2f(unsigned short h) {
    return __uint_as_float(((unsigned)h) << 16);
}

// ---- fp8 e4m3 HW converts (gfx950 OCP) ----
#if __has_builtin(__builtin_amdgcn_cvt_pk_f32_fp8)
__device__ __forceinline__ f32x2 fp8pk_lo(unsigned int p) { return __builtin_amdgcn_cvt_pk_f32_fp8(p, false); }
__device__ __forceinline__ f32x2 fp8pk_hi(unsigned int p) { return __builtin_amdgcn_cvt_pk_f32_fp8(p, true); }
#else
__device__ __forceinline__ float fp82f_s(unsigned char b) {
    __hip_fp8_e4m3 t; t.__x = (__hip_fp8_storage_t)b; return (float)t;
}
__device__ __forceinline__ f32x2 fp8pk_lo(unsigned int p) {
    f32x2 r; r.x = fp82f_s(p & 0xff); r.y = fp82f_s((p >> 8) & 0xff); return r;
}
__device__ __forceinline__ f32x2 fp8pk_hi(unsigned int p) {
    f32x2 r; r.x = fp82f_s((p >> 16) & 0xff); r.y = fp82f_s(p >> 24); return r;
}
#endif

#if __has_builtin(__builtin_amdgcn_cvt_pk_fp8_f32)
__device__ __forceinline__ unsigned int fp8enc2(float a, float b) {
    return (unsigned int)__builtin_amdgcn_cvt_pk_fp8_f32(a, b, 0, false);
}
#else
__device__ __forceinline__ unsigned int fp8enc2(float a, float b) {
    __hip_fp8_e4m3 ta(a), tb(b);
    return (unsigned int)ta.__x | ((unsigned int)tb.__x << 8);
}
#endif

// ---------------- FUSE1: trans roles (0..799) || bucketA roles (800..1190), 256 thr ----------------

__global__ __launch_bounds__(256) void k_fuse1(const float* __restrict__ W1, const float* __restrict__ W2,
                                               const float* __restrict__ resW2, const float* __restrict__ x,
                                               const int* __restrict__ src, const int* __restrict__ dst,
                                               unsigned short* __restrict__ W1F, unsigned short* __restrict__ W2F,
                                               unsigned short* __restrict__ xb,
                                               uint2* __restrict__ seg, unsigned int* __restrict__ cnt,
                                               unsigned int* __restrict__ btot) {
    int bid = blockIdx.x;
    if (bid >= 800) {
        // ---- bucketA role (byte-identical body; vb = bid - 800) ----
        __shared__ unsigned int lcnt[NBUCK];
        int vb = bid - 800;
        lcnt[threadIdx.x] = 0;
        __syncthreads();
        int base = vb * (256 * EPT) + threadIdx.x;
        int sv[EPT], dv[EPT], bk[EPT], lr[EPT];
        #pragma unroll
        for (int q = 0; q < EPT; ++q) {
            int i = base + q * 256;
            if (i < N_EDGES) { sv[q] = src[i]; dv[q] = dst[i]; }
            else dv[q] = -1;
        }
        #pragma unroll
        for (int q = 0; q < EPT; ++q) {
            if (dv[q] >= 0) {
                bk[q] = (int)((unsigned)dv[q] / NPB);
                lr[q] = atomicAdd(&lcnt[bk[q]], 1u);
            }
        }
        __syncthreads();
        cnt[vb * NBUCK + threadIdx.x] = lcnt[threadIdx.x];
        if (lcnt[threadIdx.x] > 0) atomicAdd(&btot[threadIdx.x], lcnt[threadIdx.x]);
        #pragma unroll
        for (int q = 0; q < EPT; ++q) {
            if (dv[q] >= 0 && lr[q] < SEGCAP) {
                size_t slot = ((size_t)bk[q] * BKA + vb) * SEGCAP + lr[q];
                seg[slot] = make_uint2((unsigned)sv[q], (unsigned)dv[q] - (unsigned)bk[q] * NPB);
            }
        }
        return;
    }
    int flat = bid;                               // 0..799 (1D-flattened trans roles)
    if (flat < 80) {
        // W transpose role: bx = flat%10, k0 = (flat/10)*32
        __shared__ unsigned short tile[32][33];
        int bx = flat % 10;
        const float* in;
        int Nn, n0;
        if (bx < 8)      { in = W1;    Nn = 256; n0 = bx * 32; }
        else if (bx == 8){ in = W2;    Nn = 32;  n0 = 0; }
        else             { in = resW2; Nn = 32;  n0 = 0; }
        int k0 = (flat / 10) * 32;
        int tx = threadIdx.x & 31, ty = threadIdx.x >> 5;
        #pragma unroll
        for (int r = 0; r < 4; ++r) {
            int k = k0 + ty + r * 8;
            tile[ty + r * 8][tx] = f2bf(in[(size_t)k * Nn + n0 + tx]);
        }
        __syncthreads();
        #pragma unroll
        for (int r = 0; r < 4; ++r) {
            int n = ty + r * 8;
            unsigned short val = tile[tx][n];
            int col = n0 + n;
            int kk = k0 + tx;
            if (bx < 8) {
                // fragment-major W1F (verified round 11)
                size_t idx = (((size_t)(col >> 4) * 8 + (kk >> 5)) << 9)
                           + ((((kk >> 3) & 3) * 16 + (col & 15)) << 3) + (kk & 7);
                W1F[idx] = val;
            } else {
                // fragment-major W2F: gcol 0..31 = W2 cols, 32..63 = resW2 cols
                int gcol = col + ((bx == 9) ? 32 : 0);
                size_t idx = (((size_t)(gcol >> 4) * 8 + (kk >> 5)) << 9)
                           + ((((kk >> 3) & 3) * 16 + (gcol & 15)) << 3) + (kk & 7);
                W2F[idx] = val;
            }
        }
    } else {
        int xid = flat - 80;                      // 0..719
        const size_t NCHUNK = (size_t)M_PAD * 256 / 8;
        for (size_t c = (size_t)xid * 256 + threadIdx.x; c < NCHUNK; c += (size_t)720 * 256) {
            size_t base = c * 8;
            float4 a = make_float4(0.f, 0.f, 0.f, 0.f), b = a;
            if (base < (size_t)N_NODES * 256) {
                a = *(const float4*)(x + base);
                b = *(const float4*)(x + base + 4);
            }
            ushort4 h0, h1;
            h0.x = f2bf(a.x); h0.y = f2bf(a.y); h0.z = f2bf(a.z); h0.w = f2bf(a.w);
            h1.x = f2bf(b.x); h1.y = f2bf(b.y); h1.z = f2bf(b.z); h1.w = f2bf(b.w);
            *(ushort4*)(xb + base) = h0;
            *(ushort4*)(xb + base + 4) = h1;
        }
    }
}

// ---------------- GEMM1 body (verified round 11: A LDS-staged, B fragment-major) ----------------

__device__ __forceinline__ void gemm1_body(int gblk,
                                           const unsigned short* __restrict__ xb,
                                           const unsigned short* __restrict__ W1F,
                                           const float* __restrict__ al1, const float* __restrict__ ar1,
                                           unsigned char* __restrict__ Cb8,
                                           float* __restrict__ el1, float* __restrict__ er1) {
    __shared__ unsigned short sA[64 * APAD];   // 33.8 KB
    const int t = threadIdx.x;
    const int bm0 = gblk * 64;
    const int wave = t >> 6, lane = t & 63;
    const int wm = (wave & 1) * 32, wn = (wave >> 1) * 64;
    const int lm = lane & 15, quad = lane >> 4;

    #pragma unroll
    for (int rr = 0; rr < 4; ++rr) {
        int ch = rr * 512 + t;                 // 0..2047
        int row = ch >> 5, w = ch & 31;
        bf16x8 vv = *(const bf16x8*)(xb + (size_t)(bm0 + row) * 256 + w * 8);
        *(bf16x8*)(sA + row * APAD + w * 8) = vv;
    }
    __syncthreads();

    f32x4 acc[2][4];
    #pragma unroll
    for (int i = 0; i < 2; ++i)
        #pragma unroll
        for (int j = 0; j < 4; ++j)
            #pragma unroll
            for (int r = 0; r < 4; ++r) acc[i][j][r] = 0.f;

    const unsigned short* bp[4];
    #pragma unroll
    for (int i = 0; i < 4; ++i)
        bp[i] = W1F + ((size_t)((wave >> 1) * 4 + i)) * 4096 + lane * 8;
    const unsigned short* ap[2];
    #pragma unroll
    for (int i = 0; i < 2; ++i)
        ap[i] = sA + (wm + i * 16 + lm) * APAD + quad * 8;

    bf16x8 nb[4];
    #pragma unroll
    for (int i = 0; i < 4; ++i) nb[i] = *(const bf16x8*)(bp[i]);

    #pragma unroll
    for (int q = 0; q < 8; ++q) {
        bf16x8 cb[4];
        #pragma unroll
        for (int i = 0; i < 4; ++i) cb[i] = nb[i];
        if (q < 7) {
            #pragma unroll
            for (int i = 0; i < 4; ++i) nb[i] = *(const bf16x8*)(bp[i] + (q + 1) * 512);
        }
        bf16x8 ca[2];
        #pragma unroll
        for (int i = 0; i < 2; ++i) ca[i] = *(const bf16x8*)(ap[i] + q * 32);
        #pragma unroll
        for (int mi = 0; mi < 2; ++mi)
            #pragma unroll
            for (int ni = 0; ni < 4; ++ni)
                acc[mi][ni] = __builtin_amdgcn_mfma_f32_16x16x32_bf16(ca[mi], cb[ni], acc[mi][ni], 0, 0, 0);
    }

    #pragma unroll
    for (int mi = 0; mi < 2; ++mi) {
        #pragma unroll
        for (int ni = 0; ni < 4; ++ni) {
            int col = wn + ni * 16 + lm;
            int row0 = bm0 + wm + mi * 16 + quad * 4;
            unsigned int p01 = fp8enc2(acc[mi][ni][0], acc[mi][ni][1]);
            unsigned int p23 = fp8enc2(acc[mi][ni][2], acc[mi][ni][3]);
            Cb8[(size_t)(row0 + 0) * 256 + col] = (unsigned char)(p01 & 0xff);
            Cb8[(size_t)(row0 + 1) * 256 + col] = (unsigned char)((p01 >> 8) & 0xff);
            Cb8[(size_t)(row0 + 2) * 256 + col] = (unsigned char)(p23 & 0xff);
            Cb8[(size_t)(row0 + 3) * 256 + col] = (unsigned char)((p23 >> 8) & 0xff);
        }
    }
    float alv[4], arv[4];
    #pragma unroll
    for (int ni = 0; ni < 4; ++ni) {
        int colg = wn + ni * 16 + lm;
        alv[ni] = al1[colg];
        arv[ni] = ar1[colg];
    }
    int head0 = wn >> 5;
    #pragma unroll
    for (int gg = 0; gg < 2; ++gg) {
        #pragma unroll
        for (int mi = 0; mi < 2; ++mi) {
            #pragma unroll
            for (int r = 0; r < 4; ++r) {
                float pel = acc[mi][2 * gg][r] * alv[2 * gg] + acc[mi][2 * gg + 1][r] * alv[2 * gg + 1];
                float per = acc[mi][2 * gg][r] * arv[2 * gg] + acc[mi][2 * gg + 1][r] * arv[2 * gg + 1];
                #pragma unroll
                for (int m = 1; m <= 8; m <<= 1) {
                    pel += __shfl_xor(pel, m, 64);
                    per += __shfl_xor(per, m, 64);
                }
                if (lm == 0) {
                    int row = bm0 + wm + mi * 16 + quad * 4 + r;
                    el1[row * 8 + head0 + gg] = pel;
                    er1[row * 8 + head0 + gg] = per;
                }
            }
        }
    }
}

// ---------------- FUSE2: gemm1 roles (0..781) || bucketB roles (782..1037), 512 thr ----------------

__global__ __launch_bounds__(512) void k_fuse2(const unsigned short* __restrict__ xb,
                                               const unsigned short* __restrict__ W1F,
                                               const float* __restrict__ al1, const float* __restrict__ ar1,
                                               unsigned char* __restrict__ Cb8,
                                               float* __restrict__ el1, float* __restrict__ er1,
                                               const uint2* __restrict__ seg, const unsigned int* __restrict__ cnt,
                                               const unsigned int* __restrict__ btot,
                                               int* __restrict__ rowoff, int* __restrict__ csr_src) {
    int bid = blockIdx.x;
    if (bid < GBLK) {
        gemm1_body(bid, xb, W1F, al1, ar1, Cb8, el1, er1);
        return;
    }
    // ---- bucketB role, ported to 512 threads (scan sections guarded t<256) ----
    __shared__ unsigned int hist[NPB];
    __shared__ unsigned int cursor[NPB];
    __shared__ unsigned int red[256];
    int b = bid - GBLK;
    int t = threadIdx.x;
    if (t < NPB) hist[t] = 0;
    if (t < 256) red[t] = (t < b) ? btot[t] : 0;
    __syncthreads();
    #pragma unroll
    for (int off = 128; off > 0; off >>= 1) {
        if (t < off) red[t] += red[t + off];
        __syncthreads();
    }
    unsigned int base = red[0];
    __syncthreads();
    // pass 1: count (stride 512)
    for (int s = t; s < BKA; s += 512) {
        unsigned int c = cnt[s * NBUCK + b];
        const uint2* sp = seg + ((size_t)b * BKA + s) * SEGCAP;
        for (unsigned int j = 0; j < c; ++j) {
            atomicAdd(&hist[sp[j].y], 1u);
        }
    }
    __syncthreads();
    // exclusive scan of hist[NPB] via Hillis-Steele in red[] (t<256 active)
    if (t < 256) red[t] = (t < NPB) ? hist[t] : 0;
    __syncthreads();
    for (int off = 1; off < 256; off <<= 1) {
        unsigned int val = (t >= off && t < 256) ? red[t - off] : 0u;
        __syncthreads();
        if (t < 256) red[t] += val;
        __syncthreads();
    }
    if (t < NPB) {
        unsigned int excl = red[t] - hist[t];
        cursor[t] = excl;
        int v = b * NPB + t;
        if (v < N_NODES) rowoff[v] = (int)(base + excl);
    }
    if (b == NBUCK - 1 && t == 0) rowoff[N_NODES] = N_EDGES;
    __syncthreads();
    // pass 2: place (stride 512)
    for (int s = t; s < BKA; s += 512) {
        unsigned int c = cnt[s * NBUCK + b];
        const uint2* sp = seg + ((size_t)b * BKA + s) * SEGCAP;
        for (unsigned int j = 0; j < c; ++j) {
            uint2 eg = sp[j];
            unsigned int r = atomicAdd(&cursor[eg.y], 1u);
            csr_src[base + r] = (int)eg.x;
        }
    }
}

// ---------------- L1 aggregation: one wave per dst node, shuffle-shared softmax weights ----------------

__global__ __launch_bounds__(256) void k_agg1(const unsigned char* __restrict__ feat8,
                                              const float* __restrict__ el1, const float* __restrict__ er1,
                                              const unsigned short* __restrict__ xb, const float* __restrict__ b1,
                                              const int* __restrict__ rowoff, const int* __restrict__ csr_src,
                                              unsigned short* __restrict__ y_b) {
    int v = (blockIdx.x * 256 + threadIdx.x) >> 6;
    int lane = threadIdx.x & 63;
    if (v >= M_PAD) return;
    int c0 = lane * 4;
    if (v >= N_NODES) {
        ushort4 z = {0, 0, 0, 0};
        *(ushort4*)(y_b + (size_t)v * 256 + c0) = z;
        return;
    }
    int h = lane >> 3;
    float er  = er1[v * 8 + h];
    float erc = er1[v * 8 + (lane & 7)];
    float ax = 0.f, ay = 0.f, az = 0.f, aw = 0.f, wsum = 0.f;
    int s = rowoff[v], e = rowoff[v + 1];
    int j = s;
    for (; j + 7 < e; j += 8) {
        int um = csr_src[j + (lane >> 3)];
        float elv = el1[um * 8 + (lane & 7)];
        int u[8];
        #pragma unroll
        for (int q = 0; q < 8; ++q) u[q] = __shfl(um, q * 8);
        unsigned int hv[8];
        #pragma unroll
        for (int q = 0; q < 8; ++q) hv[q] = *(const unsigned int*)(feat8 + (size_t)u[q] * 256 + c0);
        float tq = elv + erc;
        tq = fmaxf(tq, NEG_SLOPE * tq);
        float wv = __expf(tq);
        #pragma unroll
        for (int q = 0; q < 8; ++q) {
            float w = __shfl(wv, q * 8 + h);
            wsum += w;
            f32x2 lo = fp8pk_lo(hv[q]);
            f32x2 hi = fp8pk_hi(hv[q]);
            ax += w * lo.x; ay += w * lo.y; az += w * hi.x; aw += w * hi.y;
        }
    }
    for (; j + 3 < e; j += 4) {
        int u[4];
        #pragma unroll
        for (int q = 0; q < 4; ++q) u[q] = csr_src[j + q];
        float tt[4];
        #pragma unroll
        for (int q = 0; q < 4; ++q) tt[q] = el1[u[q] * 8 + h] + er;
        unsigned int hv[4];
        #pragma unroll
        for (int q = 0; q < 4; ++q) hv[q] = *(const unsigned int*)(feat8 + (size_t)u[q] * 256 + c0);
        #pragma unroll
        for (int q = 0; q < 4; ++q) {
            float tq = fmaxf(tt[q], NEG_SLOPE * tt[q]);
            float w = __expf(tq);
            wsum += w;
            f32x2 lo = fp8pk_lo(hv[q]);
            f32x2 hi = fp8pk_hi(hv[q]);
            ax += w * lo.x; ay += w * lo.y; az += w * hi.x; aw += w * hi.y;
        }
    }
    for (; j < e; ++j) {
        int u = csr_src[j];
        float tt = el1[u * 8 + h] + er;
        unsigned int hh = *(const unsigned int*)(feat8 + (size_t)u * 256 + c0);
        tt = fmaxf(tt, NEG_SLOPE * tt);
        float w = __expf(tt);
        wsum += w;
        f32x2 lo = fp8pk_lo(hh);
        f32x2 hi = fp8pk_hi(hh);
        ax += w * lo.x; ay += w * lo.y; az += w * hi.x; aw += w * hi.y;
    }
    float inv = (e > s) ? 1.f / wsum : 0.f;
    ushort4 rh = *(const ushort4*)(xb + (size_t)v * 256 + c0);
    float4 bb = *(const float4*)(b1 + c0);
    ushort4 o;
    o.x = f2bf(fmaxf(ax * inv + bf2f(rh.x) + bb.x, 0.f));
    o.y = f2bf(fmaxf(ay * inv + bf2f(rh.y) + bb.y, 0.f));
    o.z = f2bf(fmaxf(az * inv + bf2f(rh.z) + bb.z, 0.f));
    o.w = f2bf(fmaxf(aw * inv + bf2f(rh.w) + bb.w, 0.f));
    *(ushort4*)(y_b + (size_t)v * 256 + c0) = o;
}

// ---------------- GEMM2 + fused elr2: coalesced operands (A LDS-staged, B fragment-major W2F) ----------------

__global__ __launch_bounds__(256) void k_gemm2f(const unsigned short* __restrict__ Ab,
                                                const unsigned short* __restrict__ W2F,  // frag-major [32 chunks][512]
                                                const float* __restrict__ al2, const float* __restrict__ ar2,
                                                unsigned short* __restrict__ feat2b, float* __restrict__ res2,
                                                float* __restrict__ el2, float* __restrict__ er2) {
    __shared__ unsigned short sA[64 * APAD];   // 33.8 KB
    const int t = threadIdx.x;
    const int bm0 = blockIdx.x * 64;
    const int wave = t >> 6, lane = t & 63;
    const int wm = (wave & 1) * 32, wn = (wave >> 1) * 32;
    const int lm = lane & 15, quad = lane >> 4;

    // stage A-tile (64 x 256) coalesced: 2048 16B-chunks / 256 thr = 8 iters
    #pragma unroll
    for (int rr = 0; rr < 8; ++rr) {
        int ch = rr * 256 + t;
        int row = ch >> 5, w = ch & 31;
        bf16x8 vv = *(const bf16x8*)(Ab + (size_t)(bm0 + row) * 256 + w * 8);
        *(bf16x8*)(sA + row * APAD + w * 8) = vv;
    }
    __syncthreads();

    f32x4 acc[2][2];
    #pragma unroll
    for (int i = 0; i < 2; ++i)
        #pragma unroll
        for (int j = 0; j < 2; ++j)
            #pragma unroll
            for (int r = 0; r < 4; ++r) acc[i][j][r] = 0.f;

    // B: fragment-major, lane-contiguous; col-chunk = wn/16 + i
    const unsigned short* bp[2];
    #pragma unroll
    for (int i = 0; i < 2; ++i)
        bp[i] = W2F + ((size_t)((wn >> 4) + i) * 8) * 512 + lane * 8;
    const unsigned short* ap[2];
    #pragma unroll
    for (int i = 0; i < 2; ++i)
        ap[i] = sA + (wm + i * 16 + lm) * APAD + quad * 8;

    bf16x8 nb[2];
    #pragma unroll
    for (int i = 0; i < 2; ++i) nb[i] = *(const bf16x8*)(bp[i]);

    #pragma unroll
    for (int q = 0; q < 8; ++q) {
        bf16x8 cb[2];
        #pragma unroll
        for (int i = 0; i < 2; ++i) cb[i] = nb[i];
        if (q < 7) {
            #pragma unroll
            for (int i = 0; i < 2; ++i) nb[i] = *(const bf16x8*)(bp[i] + (q + 1) * 512);
        }
        bf16x8 ca[2];
        #pragma unroll
        for (int i = 0; i < 2; ++i) ca[i] = *(const bf16x8*)(ap[i] + q * 32);
        #pragma unroll
        for (int mi = 0; mi < 2; ++mi)
            #pragma unroll
            for (int ni = 0; ni < 2; ++ni)
                acc[mi][ni] = __builtin_amdgcn_mfma_f32_16x16x32_bf16(ca[mi], cb[ni], acc[mi][ni], 0, 0, 0);
    }

    #pragma unroll
    for (int mi = 0; mi < 2; ++mi) {
        #pragma unroll
        for (int ni = 0; ni < 2; ++ni) {
            int col = wn + ni * 16 + lm;  // 0..63
            #pragma unroll
            for (int r = 0; r < 4; ++r) {
                int row = bm0 + wm + mi * 16 + quad * 4 + r;
                float val = acc[mi][ni][r];
                if (col < 32) feat2b[(size_t)row * 32 + col] = f2bf(val);
                else          res2[(size_t)row * 32 + col - 32] = val;
            }
        }
    }
    if (wn == 0) {
        float alv[2], arv[2];
        #pragma unroll
        for (int ni = 0; ni < 2; ++ni) {
            alv[ni] = al2[ni * 16 + lm];
            arv[ni] = ar2[ni * 16 + lm];
        }
        #pragma unroll
        for (int mi = 0; mi < 2; ++mi) {
            #pragma unroll
            for (int r = 0; r < 4; ++r) {
                float pel = acc[mi][0][r] * alv[0] + acc[mi][1][r] * alv[1];
                float per = acc[mi][0][r] * arv[0] + acc[mi][1][r] * arv[1];
                #pragma unroll
                for (int m = 1; m <= 8; m <<= 1) {
                    pel += __shfl_xor(pel, m, 64);
                    per += __shfl_xor(per, m, 64);
                }
                if (lm == 0) {
                    int row = bm0 + wm + mi * 16 + quad * 4 + r;
                    el2[row] = pel;
                    er2[row] = per;
                }
            }
        }
    }
}

// ---------------- L2 aggregation (round-12 verified body) ----------------

__global__ __launch_bounds__(256) void k_agg2(const unsigned short* __restrict__ feat2b,
                                              const float* __restrict__ el2, const float* __restrict__ er2,
                                              const float* __restrict__ res2, const float* __restrict__ b2,
                                              const int* __restrict__ rowoff, const int* __restrict__ csr_src,
                                              float* __restrict__ out) {
    int g = blockIdx.x * 256 + threadIdx.x;
    int v = g >> 5;
    int c = g & 31;
    if (v >= N_NODES) return;
    float er = er2[v];
    float acc = 0.f, wsum = 0.f;
    int s = rowoff[v], e = rowoff[v + 1];
    int j = s;
    for (; j + 3 < e; j += 4) {
        int u[4];
        #pragma unroll
        for (int q = 0; q < 4; ++q) u[q] = csr_src[j + q];
        float tt[4];
        #pragma unroll
        for (int q = 0; q < 4; ++q) tt[q] = el2[u[q]] + er;
        unsigned short fv[4];
        #pragma unroll
        for (int q = 0; q < 4; ++q) fv[q] = feat2b[(size_t)u[q] * 32 + c];
        #pragma unroll
        for (int q = 0; q < 4; ++q) {
            float tq = fmaxf(tt[q], NEG_SLOPE * tt[q]);
            float w = __expf(tq);
            wsum += w;
            acc += w * bf2f(fv[q]);
        }
    }
    for (; j < e; ++j) {
        int u = csr_src[j];
        float t = el2[u] + er;
        t = fmaxf(t, NEG_SLOPE * t);
        float w = __expf(t);
        wsum += w;
        acc += w * bf2f(feat2b[(size_t)u * 32 + c]);
    }
    float inv = (e > s) ? 1.f / wsum : 0.f;
    out[(size_t)v * 32 + c] = acc * inv + res2[(size_t)v * 32 + c] + b2[c];
}

// ---------------- launch ----------------

extern "C" void kernel_launch(void* const* d_in, const int* in_sizes, int n_in,
                              void* d_out, int out_size, void* d_ws, size_t ws_size,
                              hipStream_t stream) {
    const float* x     = (const float*)d_in[0];
    const int*   src   = (const int*)d_in[1];
    const int*   dst   = (const int*)d_in[2];
    const float* W1    = (const float*)d_in[3];
    const float* al1   = (const float*)d_in[4];
    const float* ar1   = (const float*)d_in[5];
    const float* b1    = (const float*)d_in[6];
    const float* W2    = (const float*)d_in[7];
    const float* al2   = (const float*)d_in[8];
    const float* ar2   = (const float*)d_in[9];
    const float* resW2 = (const float*)d_in[10];
    const float* b2    = (const float*)d_in[11];
    float* out = (float*)d_out;

    char* ws = (char*)d_ws;
    size_t off = 0;
    auto alloc = [&](size_t bytes) {
        void* p = ws + off;
        off += (bytes + 255) & ~(size_t)255;
        return p;
    };
    unsigned short* xb     = (unsigned short*)alloc((size_t)M_PAD * 256 * 2);
    unsigned char*  feat8  = (unsigned char*)alloc((size_t)M_PAD * 256);
    unsigned short* y_b    = (unsigned short*)alloc((size_t)M_PAD * 256 * 2);
    unsigned short* W1F    = (unsigned short*)alloc((size_t)256 * 256 * 2);
    unsigned short* W2F    = (unsigned short*)alloc((size_t)64 * 256 * 2);
    unsigned short* feat2b = (unsigned short*)alloc((size_t)M_PAD * 32 * 2);
    float* res2   = (float*)alloc((size_t)M_PAD * 32 * 4);
    float* el1    = (float*)alloc((size_t)M_PAD * 8 * 4);
    float* er1    = (float*)alloc((size_t)M_PAD * 8 * 4);
    float* el2    = (float*)alloc((size_t)M_PAD * 4);
    float* er2    = (float*)alloc((size_t)M_PAD * 4);
    int*   rowoff = (int*)alloc((size_t)(N_NODES + 1) * 4);
    int*   csr    = (int*)alloc((size_t)N_EDGES * 4);
    uint2* seg    = (uint2*)alloc((size_t)NBUCK * BKA * SEGCAP * 8);
    unsigned int* cnt  = (unsigned int*)alloc((size_t)BKA * NBUCK * 4);
    unsigned int* btot = (unsigned int*)alloc((size_t)NBUCK * 4);
    (void)ws_size;

    // btot zero (graph-capturable)
    hipMemsetAsync(btot, 0, (size_t)NBUCK * 4, stream);

    // FUSE1: trans || bucketA
    k_fuse1<<<FUSE1_T, 256, 0, stream>>>(W1, W2, resW2, x, src, dst, W1F, W2F, xb, seg, cnt, btot);

    // FUSE2: gemm1 || bucketB
    k_fuse2<<<FUSE2_T, 512, 0, stream>>>(xb, W1F, al1, ar1, feat8, el1, er1, seg, cnt, btot, rowoff, csr);

    // Layer 1 aggregation
    k_agg1<<<(M_PAD * 64) / 256, 256, 0, stream>>>(feat8, el1, er1, xb, b1, rowoff, csr, y_b);

    // Layer 2
    k_gemm2f<<<M_PAD / 64, 256, 0, stream>>>(y_b, W2F, al2, ar2, feat2b, res2, el2, er2);
    k_agg2<<<(N_NODES * 32) / 256, 256, 0, stream>>>(feat2b, el2, er2, res2, b2, rowoff, csr, out);
}